// Round 11
// baseline (282.484 us; speedup 1.0000x reference)
//
#include <hip/hip_runtime.h>

#define DI __device__ __forceinline__

typedef __bf16 bf16_t;
typedef bf16_t bf16x8 __attribute__((ext_vector_type(8)));
typedef float f32x4 __attribute__((ext_vector_type(4)));
typedef ushort ushort8v __attribute__((ext_vector_type(8)));

static constexpr int NNODE = 100, WIN = 128, GH = 256, DH = 64, OUTC = 128, NB = 256;
static constexpr int NTOT = NB * NNODE;   // 25600
static constexpr int NE = 409600;
static constexpr int FFK = 6 * WIN;       // 768
static constexpr size_t CB = (size_t)NNODE * NB * FFK;
static constexpr size_t HB = (size_t)NTOT * GH;
static constexpr int CVT_BLKS = 23264;
static constexpr int NSEG = 64, SEGE = NE / NSEG;      // 64 segs x 6400 edges
static constexpr int NPK = NTOT / 2;                    // 12800 packed counters

DI ushort f2bf(float f) {
  union { float f; unsigned u; } v; v.f = f;
  unsigned r = v.u + 0x7fffu + ((v.u >> 16) & 1u);
  return (ushort)(r >> 16);
}
DI float bf2f(ushort s) {
  union { unsigned u; float f; } v; v.u = ((unsigned)s) << 16; return v.f;
}

DI void gload16(const void* g, void* l) {
  __builtin_amdgcn_global_load_lds((const __attribute__((address_space(1))) void*)g,
                                   (__attribute__((address_space(3))) void*)l, 16, 0, 0);
}

// ================= device bodies =================

DI void cvt_body(int bx, const float* s0, const float* s1, const float* s2, const float* s3,
                 ushort* d0, ushort* d1, ushort* d2, ushort* d3) {
  int j = bx * 256 + threadIdx.x;   // vec4 index
  const float* s; ushort* d;
  if (j < 19660800 / 4) { s = s0; d = d0; }
  else if ((j -= 19660800 / 4) < 3276800 / 4) { s = s1; d = d1; }
  else if ((j -= 3276800 / 4) < 819200 / 4) { s = s2; d = d2; }
  else { j -= 819200 / 4; s = s3; d = d3; }
  float4 v = reinterpret_cast<const float4*>(s)[j];
  ushort4 o;
  o.x = f2bf(v.x); o.y = f2bf(v.y); o.z = f2bf(v.z); o.w = f2bf(v.w);
  reinterpret_cast<ushort4*>(d)[j] = o;
}

// LDS-privatized segmented histogram with rank capture (NO global atomics).
DI void histseg_body(int bx, const int* e1d, const int* e2d,
                     ushort* rank_local, uint* segcnt, uint* cnt /*LDS, 12800*/) {
  int set = bx & 1, seg = bx >> 1;
  int tid = threadIdx.x;
#pragma unroll
  for (int k = 0; k < NPK / 256; ++k) cnt[tid + k * 256] = 0;
  __syncthreads();
  const int* dstp = (set ? e2d : e1d) + seg * SEGE;
  ushort* rl = rank_local + set * NE + seg * SEGE;
#pragma unroll
  for (int k = 0; k < SEGE / 256; ++k) {
    int i = k * 256 + tid;
    int d = dstp[i];
    uint sh = (d & 1) * 16;
    uint old = atomicAdd(&cnt[d >> 1], 1u << sh);
    rl[i] = (ushort)((old >> sh) & 0xffffu);
  }
  __syncthreads();
  uint* sc = segcnt + (size_t)(set * NSEG + seg) * NPK;
#pragma unroll
  for (int k = 0; k < NPK / 256; ++k) sc[tid + k * 256] = cnt[tid + k * 256];
}

// atomic-free CSR fill using segment base + local rank
DI void fill_body(int bx, const int* e1, const int* e2, const int* offs,
                  const ushort* rank_local, const uint* segbase, int* csr) {
  int i = bx * 256 + threadIdx.x;          // [0, 2*NE)
  int set = i >= NE;
  int ii = i - set * NE;
  const int* e = set ? e2 : e1;
  int d = e[NE + ii];
  int seg = ii / SEGE;
  uint b32 = segbase[(size_t)(set * NSEG + seg) * NPK + (d >> 1)];
  int base = (b32 >> ((d & 1) * 16)) & 0xffff;
  int pos = offs[set * (NTOT + 1) + d] + base + rank_local[i];
  csr[set * NE + pos] = e[ii];
}

// 256-thread scan over one edge set (100 elems/thread, two-pass)
DI void scan_body(int set, const int* deg_, int* offs_, float* norm_) {
  const int* deg = deg_ + set * NTOT;
  int* offs = offs_ + set * (NTOT + 1);
  float* norm = norm_ + set * NTOT;
  __shared__ int part[256];
  int t = threadIdx.x;
  int base = t * 100;
  int s = 0;
  for (int j = 0; j < 100; ++j) s += deg[base + j];
  part[t] = s;
  __syncthreads();
  for (int d = 1; d < 256; d <<= 1) {
    int vv = (t >= d) ? part[t - d] : 0;
    __syncthreads();
    part[t] += vv;
    __syncthreads();
  }
  int run = (t > 0) ? part[t - 1] : 0;
  for (int j = 0; j < 100; ++j) {
    int dv = deg[base + j];
    offs[base + j] = run;
    norm[base + j] = rsqrtf((float)(dv + 1));
    run += dv;
  }
  if (t == 255) offs[NTOT] = part[255];
}

DI void conv_body(int bx, const float* x1, const float* x2,
                  const float* w3, const float* b3, const float* w5, const float* b5,
                  const float* w7, const float* b7, ushort* c, float* xs /*LDS [16][136]*/) {
  const int t = threadIdx.x;
  const int rowi = t >> 4;
  const int idx = t & 15;
  int r = bx * 16 + rowi;
  int br = r >= NTOT;
  int rr = r - br * NTOT;
  const float* x = br ? x2 : x1;
  int b = rr / 100, node = rr - b * 100;

  float* row = xs + rowi * 136;
  const int w0 = idx * 8;
  float4 v0 = *reinterpret_cast<const float4*>(x + (size_t)rr * WIN + w0);
  float4 v1 = *reinterpret_cast<const float4*>(x + (size_t)rr * WIN + w0 + 4);
  *reinterpret_cast<float4*>(&row[4 + w0]) = v0;
  *reinterpret_cast<float4*>(&row[4 + w0 + 4]) = v1;
  if (idx == 0) { row[0] = 0.f; row[1] = 0.f; row[2] = 0.f; row[3] = 0.f; }
  if (idx == 15) { row[132] = 0.f; row[133] = 0.f; row[134] = 0.f; row[135] = 0.f; }
  __syncthreads();

  float xv[14];
#pragma unroll
  for (int j = 0; j < 14; ++j) xv[j] = row[1 + w0 + j];

  const float* W3 = w3 + node * 6;  const float* B3 = b3 + node * 2;
  const float* W5 = w5 + node * 10; const float* B5 = b5 + node * 2;
  const float* W7 = w7 + node * 14; const float* B7 = b7 + node * 2;
  ushort* out = c + (size_t)br * CB + (size_t)(node * NB + b) * FFK + w0;

#pragma unroll
  for (int ch = 0; ch < 2; ++ch) {
    float k3[3], k5[5], k7[7];
#pragma unroll
    for (int j = 0; j < 3; ++j) k3[j] = W3[ch * 3 + j];
#pragma unroll
    for (int j = 0; j < 5; ++j) k5[j] = W5[ch * 5 + j];
#pragma unroll
    for (int j = 0; j < 7; ++j) k7[j] = W7[ch * 7 + j];
    float bb3 = B3[ch], bb5 = B5[ch], bb7 = B7[ch];
    ushort8v o3, o5, o7;
#pragma unroll
    for (int p = 0; p < 8; ++p) {
      float a3 = bb3, a5 = bb5, a7 = bb7;
#pragma unroll
      for (int j = 0; j < 3; ++j) a3 += k3[j] * xv[p + 2 + j];
#pragma unroll
      for (int j = 0; j < 5; ++j) a5 += k5[j] * xv[p + 1 + j];
#pragma unroll
      for (int j = 0; j < 7; ++j) a7 += k7[j] * xv[p + j];
      o3[p] = f2bf(fmaxf(a3, 0.f));
      o5[p] = f2bf(fmaxf(a5, 0.f));
      o7[p] = f2bf(fmaxf(a7, 0.f));
    }
    *reinterpret_cast<ushort8v*>(out + (0 + ch) * WIN) = o3;
    *reinterpret_cast<ushort8v*>(out + (2 + ch) * WIN) = o5;
    *reinterpret_cast<ushort8v*>(out + (4 + ch) * WIN) = o7;
  }
}

// ---------- BT GEMM body (XOR-swizzled LDS) ----------
template <int MODE>
DI void gemm_body(int bx, int by, const ushort* __restrict__ A, const ushort* __restrict__ A2,
                  const ushort* __restrict__ Bm, ushort* __restrict__ obf,
                  float* __restrict__ of, const float* __restrict__ bias) {
  constexpr int BN = (MODE == 2) ? 64 : 128;
  constexpr int KT = (MODE == 0) ? 12 : (MODE == 1) ? 4 : (MODE == 2) ? 8 : 4;
  constexpr int LDA = (MODE == 0) ? 768 : (MODE == 1) ? 256 : (MODE == 2) ? 256 : 6400;
  constexpr int LDB = (MODE == 0) ? 768 : (MODE == 1) ? 256 : (MODE == 2) ? 512 : 6400;
  constexpr int MF = (MODE == 2) ? 2 : 4;
  constexpr int NF = 4;

  __shared__ ushort As[128 * 64];
  __shared__ ushort Bs[BN * 64];

  const int tid = threadIdx.x, wv = tid >> 6, lane = tid & 63;
  const int j8 = (((lane & 7) ^ (lane >> 3)) - (lane & 7)) * 8;

  int mt = 0, nt = 0, node = 0, kbase = 0, br = 0;
  if constexpr (MODE == 0) {
    int h = bx;
    int s = (h & 7) * 100 + (h >> 3);
    nt = s & 1; int rest = s >> 1;
    mt = rest & 1; int yy = rest >> 1;
    br = yy >= 100; node = yy - br * 100;
  } else if constexpr (MODE == 1) {
    int h = bx;
    int s = (h & 7) * 100 + (h >> 3);
    nt = s & 1; int rest = s >> 1;
    br = rest >= 200; mt = rest - br * 200;
  } else if constexpr (MODE == 2) { mt = bx; node = by; }
  else { mt = bx; kbase = by * 256; }

  const ushort* Ab = nullptr; const ushort* Bb = nullptr;
  if constexpr (MODE == 0) { Ab = A + (size_t)br * CB + (size_t)node * (NB * FFK) + (size_t)mt * 128 * FFK;
                             Bb = Bm + (size_t)node * (GH * FFK) + (size_t)nt * 128 * FFK; }
  else if constexpr (MODE == 1) { Ab = A + (size_t)br * HB + (size_t)mt * 128 * GH;
                                  Bb = Bm + (size_t)nt * 128 * GH; }
  else if constexpr (MODE == 2) { Bb = Bm + (size_t)node * (DH * 512); }
  else { Ab = A + (size_t)mt * 128 * 6400 + kbase; Bb = Bm + kbase; }

  const int wr = (MODE == 2) ? wv : (wv >> 1);
  const int wc = (MODE == 2) ? 0 : (wv & 1);

  f32x4 acc[MF][NF] = {};

  for (int kt = 0; kt < KT; ++kt) {
    const int k0 = kt * 64;
    __syncthreads();
#pragma unroll
    for (int it = 0; it < 4; ++it) {
      int rb = it * 32 + wv * 8;
      int row = rb + (lane >> 3);
      const ushort* gp;
      if constexpr (MODE == 2) {
        int b_ = mt * 128 + row;
        const ushort* src = (k0 < 256) ? A : A2;
        gp = src + (size_t)(b_ * NNODE + node) * GH + (k0 & 255) + (lane & 7) * 8 + j8;
      } else {
        gp = Ab + (size_t)row * LDA + k0 + (lane & 7) * 8 + j8;
      }
      gload16(gp, &As[rb * 64]);
    }
#pragma unroll
    for (int it = 0; it < BN / 32; ++it) {
      int rb = it * 32 + wv * 8;
      int row = rb + (lane >> 3);
      gload16(Bb + (size_t)row * LDB + k0 + (lane & 7) * 8 + j8, &Bs[rb * 64]);
    }
    __syncthreads();
#pragma unroll
    for (int kk = 0; kk < 2; ++kk) {
      const int ch8 = ((kk * 4 + (lane >> 4)) ^ (lane & 7)) * 8;
      bf16x8 af[MF], bfr[NF];
#pragma unroll
      for (int m = 0; m < MF; ++m) {
        int rr = wr * (MF * 16) + m * 16 + (lane & 15);
        af[m] = *reinterpret_cast<const bf16x8*>(&As[rr * 64 + ch8]);
      }
#pragma unroll
      for (int n = 0; n < NF; ++n) {
        int rr = wc * 64 + n * 16 + (lane & 15);
        bfr[n] = *reinterpret_cast<const bf16x8*>(&Bs[rr * 64 + ch8]);
      }
#pragma unroll
      for (int m = 0; m < MF; ++m)
#pragma unroll
        for (int n = 0; n < NF; ++n)
          acc[m][n] = __builtin_amdgcn_mfma_f32_16x16x32_bf16(af[m], bfr[n], acc[m][n], 0, 0, 0);
    }
  }

  const int lrow = (lane >> 4) * 4, lcol = lane & 15;
#pragma unroll
  for (int m = 0; m < MF; ++m) {
#pragma unroll
    for (int n = 0; n < NF; ++n) {
      int cc = wc * 64 + n * 16 + lcol;
#pragma unroll
      for (int rg = 0; rg < 4; ++rg) {
        int rr = wr * (MF * 16) + m * 16 + lrow + rg;
        float val = acc[m][n][rg];
        if constexpr (MODE == 0) {
          int b_ = mt * 128 + rr;
          int col = nt * 128 + cc;
          val = fmaxf(val + bias[node * GH + col], 0.f);
          obf[(size_t)br * HB + (size_t)(b_ * NNODE + node) * GH + col] = f2bf(val);
        } else if constexpr (MODE == 1) {
          int R = mt * 128 + rr;
          int col = nt * 128 + cc;
          obf[(size_t)br * HB + (size_t)R * GH + col] = f2bf(val * bias[br * NTOT + R]);
        } else if constexpr (MODE == 2) {
          int b_ = mt * 128 + rr;
          val = fmaxf(val + bias[node * DH + cc], 0.f);
          obf[(size_t)b_ * (NNODE * DH) + node * DH + cc] = f2bf(val);
        } else {
          int R = mt * 128 + rr;
          if (by == 0) val += bias[cc];
          atomicAdd(&of[R * OUTC + cc], val);
        }
      }
    }
  }
}

// ================= fused launch kernels =================

__global__ __launch_bounds__(256) void fused1_k(
    const float* __restrict__ Wff, const float* __restrict__ Wd,
    const float* __restrict__ Wfc, const float* __restrict__ Wg,
    ushort* __restrict__ Wffb, ushort* __restrict__ Wdb,
    ushort* __restrict__ Wfcb, ushort* __restrict__ Wgb,
    const int* __restrict__ e1d, const int* __restrict__ e2d,
    ushort* __restrict__ rank_local, uint* __restrict__ segcnt,
    const float* __restrict__ x1, const float* __restrict__ x2,
    const float* __restrict__ w3, const float* __restrict__ b3,
    const float* __restrict__ w5, const float* __restrict__ b5,
    const float* __restrict__ w7, const float* __restrict__ b7,
    ushort* __restrict__ c) {
  __shared__ uint smem[NPK];   // 50 KB; conv reuses as float[16][136]
  int bx = blockIdx.x;
  if (bx < 128) histseg_body(bx, e1d, e2d, rank_local, segcnt, smem);
  else if (bx < 3328) conv_body(bx - 128, x1, x2, w3, b3, w5, b5, w7, b7, c, (float*)smem);
  else cvt_body(bx - 3328, Wff, Wd, Wfc, Wg, Wffb, Wdb, Wfcb, Wgb);
}

__global__ __launch_bounds__(256) void segscan_k(const uint* __restrict__ segcnt,
                                                 uint* __restrict__ segbase, int* __restrict__ deg) {
  int set = blockIdx.y;
  int p = blockIdx.x * 256 + threadIdx.x;   // [0, NPK)
  uint lo = 0, hi = 0;
  const uint* sc = segcnt + (size_t)set * NSEG * NPK + p;
  uint* sb = segbase + (size_t)set * NSEG * NPK + p;
  for (int s = 0; s < NSEG; ++s) {
    uint v = sc[(size_t)s * NPK];
    sb[(size_t)s * NPK] = lo | (hi << 16);
    lo += v & 0xffffu; hi += v >> 16;
  }
  reinterpret_cast<int2*>(deg)[set * NPK + p] = make_int2((int)lo, (int)hi);
}

__global__ __launch_bounds__(256) void scan_k(const int* __restrict__ deg,
                                              int* __restrict__ offs, float* __restrict__ nrm) {
  scan_body(blockIdx.x, deg, offs, nrm);
}

__global__ __launch_bounds__(256) void fused3_k(
    const ushort* __restrict__ cbuf, const ushort* __restrict__ Wffb,
    ushort* __restrict__ h, const float* __restrict__ bff,
    const int* __restrict__ e1, const int* __restrict__ e2,
    const int* __restrict__ offs, const ushort* __restrict__ rank_local,
    const uint* __restrict__ segbase, int* __restrict__ csr) {
  if ((int)blockIdx.x < 800)
    gemm_body<0>(blockIdx.x, 0, cbuf, nullptr, Wffb, h, nullptr, bff);
  else
    fill_body(blockIdx.x - 800, e1, e2, offs, rank_local, segbase, csr);
}

template <int MODE>
__global__ __launch_bounds__(256) void gemm_k(const ushort* __restrict__ A, const ushort* __restrict__ A2,
                                              const ushort* __restrict__ Bm, ushort* __restrict__ obf,
                                              float* __restrict__ of, const float* __restrict__ bias) {
  gemm_body<MODE>(blockIdx.x, blockIdx.y, A, A2, Bm, obf, of, bias);
}

// ---------- GCN aggregation, XCD column-sharded, wave-per-(node,slice) ----------
// blockIdx.x = i*8 + c, c = br*4 + slice -> XCD c (keeps per-XCD L2 slice 3.3 MB).
// One wave per node-slice: 8 edge-streams x 8 lanes x 16B (full 128B slice row per stream).
// 2-deep unroll: 16 gathers (8 KB) in flight per wave; shfl_xor tree combines streams.
__global__ __launch_bounds__(256) void agg_k(const ushort* __restrict__ xw_, const int* __restrict__ offs_,
                                             const int* __restrict__ csr_, const float* __restrict__ norm_,
                                             const float* __restrict__ bg, ushort* __restrict__ hg_) {
  int bid = blockIdx.x;
  int c = bid & 7;
  int i = bid >> 3;                    // 0..6399
  int br = c >> 2, slice = c & 3;
  int wv = threadIdx.x >> 6;           // wave 0..3
  int v = i * 4 + wv;
  int lane = threadIdx.x & 63;
  int stream = lane >> 3;              // 0..7 edge streams
  int l8 = lane & 7;                   // position within stream
  int col = slice * 64 + l8 * 8;       // 8 cols (16 B) per lane

  const ushort* xw = xw_ + (size_t)br * HB;
  const int* offs = offs_ + br * (NTOT + 1);
  const int* csr = csr_ + br * NE;
  const float* norm = norm_ + br * NTOT;
  ushort* hg = hg_ + (size_t)br * HB;
  const ushort* base = xw + col;

  float a[8] = {0.f, 0.f, 0.f, 0.f, 0.f, 0.f, 0.f, 0.f};
  if (stream == 0) {                   // self loop
    ushort8v q = *reinterpret_cast<const ushort8v*>(base + (size_t)v * GH);
#pragma unroll
    for (int p = 0; p < 8; ++p) a[p] += bf2f(q[p]);
  }
  int e0 = offs[v], e1v = offs[v + 1];
  int j = e0 + stream;
  for (; j + 8 < e1v; j += 16) {       // 2 edges per stream in flight
    int s0 = csr[j], s1 = csr[j + 8];
    ushort8v q0 = *reinterpret_cast<const ushort8v*>(base + (size_t)s0 * GH);
    ushort8v q1 = *reinterpret_cast<const ushort8v*>(base + (size_t)s1 * GH);
#pragma unroll
    for (int p = 0; p < 8; ++p) a[p] += bf2f(q0[p]) + bf2f(q1[p]);
  }
  if (j < e1v) {
    int s0 = csr[j];
    ushort8v q0 = *reinterpret_cast<const ushort8v*>(base + (size_t)s0 * GH);
#pragma unroll
    for (int p = 0; p < 8; ++p) a[p] += bf2f(q0[p]);
  }
  // combine the 8 streams (xor tree over lane groups of 8)
#pragma unroll
  for (int d = 8; d < 64; d <<= 1)
#pragma unroll
    for (int p = 0; p < 8; ++p) a[p] += __shfl_xor(a[p], d);

  if (stream == 0) {
    float nv = norm[v];
    ushort8v o;
#pragma unroll
    for (int p = 0; p < 8; ++p) o[p] = f2bf(fmaxf(nv * a[p] + bg[col + p], 0.f));
    *reinterpret_cast<ushort8v*>(hg + (size_t)v * GH + col) = o;
  }
}

extern "C" void kernel_launch(void* const* d_in, const int* in_sizes, int n_in,
                              void* d_out, int out_size, void* d_ws, size_t ws_size,
                              hipStream_t stream) {
  const float* x1 = (const float*)d_in[0];
  const float* x2 = (const float*)d_in[1];
  const int* e1 = (const int*)d_in[2];
  const int* e2 = (const int*)d_in[3];
  const float* w3 = (const float*)d_in[4];  const float* b3 = (const float*)d_in[5];
  const float* w5 = (const float*)d_in[6];  const float* b5 = (const float*)d_in[7];
  const float* w7 = (const float*)d_in[8];  const float* b7 = (const float*)d_in[9];
  const float* Wff = (const float*)d_in[10]; const float* bff = (const float*)d_in[11];
  const float* Wg = (const float*)d_in[12];  const float* bg = (const float*)d_in[13];
  const float* Wd = (const float*)d_in[14];  const float* bd = (const float*)d_in[15];
  const float* Wfc = (const float*)d_in[16]; const float* bfc = (const float*)d_in[17];
  float* out = (float*)d_out;

  char* ws = (char*)d_ws;
  size_t off = 0;
  auto alloc = [&](size_t bytes) -> char* {
    char* p = ws + off;
    off = (off + bytes + 255) & ~(size_t)255;
    return p;
  };
  ushort* Wffb = (ushort*)alloc(19660800ull * 2);
  ushort* Wdb  = (ushort*)alloc(3276800ull * 2);
  ushort* Wfcb = (ushort*)alloc(819200ull * 2);
  ushort* Wgb  = (ushort*)alloc(65536ull * 2);
  ushort* cbuf = (ushort*)alloc(2 * CB * 2);   // both branches; later aliased as du
  ushort* h    = (ushort*)alloc(2 * HB * 2);   // both branches; later aliased as hg
  ushort* xw   = (ushort*)alloc(2 * HB * 2);   // both branches
  int* deg     = (int*)alloc(2 * NTOT * 4);
  int* offs    = (int*)alloc(2 * (NTOT + 1) * 4);
  ushort* rankl = (ushort*)alloc(2 * NE * 2);
  uint* segcnt  = (uint*)alloc((size_t)2 * NSEG * NPK * 4);
  uint* segbase = (uint*)alloc((size_t)2 * NSEG * NPK * 4);
  int* csr     = (int*)alloc(2 * NE * 4);
  float* nrm   = (float*)alloc(2 * NTOT * 4);
  ushort* du = cbuf;  // alias: cbuf free after FF GEMM

  hipMemsetAsync(out, 0, (size_t)out_size * 4, stream);

  // F1: histseg (LDS histogram, no global atomics) + conv + cvt, all BW-bound
  fused1_k<<<128 + 3200 + CVT_BLKS, 256, 0, stream>>>(
      Wff, Wd, Wfc, Wg, Wffb, Wdb, Wfcb, Wgb,
      e1 + NE, e2 + NE, rankl, segcnt,
      x1, x2, w3, b3, w5, b5, w7, b7, cbuf);
  segscan_k<<<dim3(NPK / 256, 2), 256, 0, stream>>>(segcnt, segbase, deg);
  scan_k<<<2, 256, 0, stream>>>(deg, offs, nrm);
  // F3: FF GEMM || atomic-free CSR fill
  fused3_k<<<4000, 256, 0, stream>>>(cbuf, Wffb, h, bff, e1, e2, offs, rankl, segbase, csr);

  gemm_k<1><<<800, 256, 0, stream>>>(h, nullptr, Wgb, xw, nullptr, nrm);
  // agg: XCD column-sharded, one wave per (node, slice); 6400 node-groups x 8 combos
  agg_k<<<51200, 256, 0, stream>>>(xw, offs, csr, nrm, bg, h);   // hg overwrites h

  gemm_k<2><<<dim3(2, 100), 256, 0, stream>>>(h, h + HB, Wdb, du, nullptr, bd);
  gemm_k<3><<<dim3(2, 25), 256, 0, stream>>>(du, nullptr, Wfcb, nullptr, out, bfc);
}

// Round 12
// 239.592 us; speedup vs baseline: 1.1790x; 1.1790x over previous
//
#include <hip/hip_runtime.h>

#define DI __device__ __forceinline__

typedef __bf16 bf16_t;
typedef bf16_t bf16x8 __attribute__((ext_vector_type(8)));
typedef float f32x4 __attribute__((ext_vector_type(4)));
typedef ushort ushort8v __attribute__((ext_vector_type(8)));

static constexpr int NNODE = 100, WIN = 128, GH = 256, DH = 64, OUTC = 128, NB = 256;
static constexpr int NTOT = NB * NNODE;   // 25600
static constexpr int NE = 409600;
static constexpr int FFK = 6 * WIN;       // 768
static constexpr size_t CB = (size_t)NNODE * NB * FFK;
static constexpr size_t HB = (size_t)NTOT * GH;
static constexpr int CVT_BLKS = 23264;
static constexpr int NSEG = 64, SEGE = NE / NSEG;      // 64 segs x 6400 edges
static constexpr int NPK = NTOT / 2;                    // 12800 packed counters

DI ushort f2bf(float f) {
  union { float f; unsigned u; } v; v.f = f;
  unsigned r = v.u + 0x7fffu + ((v.u >> 16) & 1u);
  return (ushort)(r >> 16);
}
DI float bf2f(ushort s) {
  union { unsigned u; float f; } v; v.u = ((unsigned)s) << 16; return v.f;
}
DI float u2f(uint u) { union { uint u; float f; } v; v.u = u; return v.f; }

DI void gload16(const void* g, void* l) {
  __builtin_amdgcn_global_load_lds((const __attribute__((address_space(1))) void*)g,
                                   (__attribute__((address_space(3))) void*)l, 16, 0, 0);
}

// ================= device bodies =================

DI void cvt_body(int bx, const float* s0, const float* s1, const float* s2, const float* s3,
                 ushort* d0, ushort* d1, ushort* d2, ushort* d3) {
  int j = bx * 256 + threadIdx.x;   // vec4 index
  const float* s; ushort* d;
  if (j < 19660800 / 4) { s = s0; d = d0; }
  else if ((j -= 19660800 / 4) < 3276800 / 4) { s = s1; d = d1; }
  else if ((j -= 3276800 / 4) < 819200 / 4) { s = s2; d = d2; }
  else { j -= 819200 / 4; s = s3; d = d3; }
  float4 v = reinterpret_cast<const float4*>(s)[j];
  ushort4 o;
  o.x = f2bf(v.x); o.y = f2bf(v.y); o.z = f2bf(v.z); o.w = f2bf(v.w);
  reinterpret_cast<ushort4*>(d)[j] = o;
}

// LDS-privatized segmented histogram with rank capture (NO global atomics).
DI void histseg_body(int bx, const int* e1d, const int* e2d,
                     ushort* rank_local, uint* segcnt, uint* cnt /*LDS, 12800*/) {
  int set = bx & 1, seg = bx >> 1;
  int tid = threadIdx.x;
#pragma unroll
  for (int k = 0; k < NPK / 256; ++k) cnt[tid + k * 256] = 0;
  __syncthreads();
  const int* dstp = (set ? e2d : e1d) + seg * SEGE;
  ushort* rl = rank_local + set * NE + seg * SEGE;
#pragma unroll
  for (int k = 0; k < SEGE / 256; ++k) {
    int i = k * 256 + tid;
    int d = dstp[i];
    uint sh = (d & 1) * 16;
    uint old = atomicAdd(&cnt[d >> 1], 1u << sh);
    rl[i] = (ushort)((old >> sh) & 0xffffu);
  }
  __syncthreads();
  uint* sc = segcnt + (size_t)(set * NSEG + seg) * NPK;
#pragma unroll
  for (int k = 0; k < NPK / 256; ++k) sc[tid + k * 256] = cnt[tid + k * 256];
}

// atomic-free CSR fill using segment base + local rank
DI void fill_body(int bx, const int* e1, const int* e2, const int* offs,
                  const ushort* rank_local, const uint* segbase, int* csr) {
  int i = bx * 256 + threadIdx.x;          // [0, 2*NE)
  int set = i >= NE;
  int ii = i - set * NE;
  const int* e = set ? e2 : e1;
  int d = e[NE + ii];
  int seg = ii / SEGE;
  uint b32 = segbase[(size_t)(set * NSEG + seg) * NPK + (d >> 1)];
  int base = (b32 >> ((d & 1) * 16)) & 0xffff;
  int pos = offs[set * (NTOT + 1) + d] + base + rank_local[i];
  csr[set * NE + pos] = e[ii];
}

// 256-thread scan over one edge set (100 elems/thread, two-pass)
DI void scan_body(int set, const int* deg_, int* offs_, float* norm_) {
  const int* deg = deg_ + set * NTOT;
  int* offs = offs_ + set * (NTOT + 1);
  float* norm = norm_ + set * NTOT;
  __shared__ int part[256];
  int t = threadIdx.x;
  int base = t * 100;
  int s = 0;
  for (int j = 0; j < 100; ++j) s += deg[base + j];
  part[t] = s;
  __syncthreads();
  for (int d = 1; d < 256; d <<= 1) {
    int vv = (t >= d) ? part[t - d] : 0;
    __syncthreads();
    part[t] += vv;
    __syncthreads();
  }
  int run = (t > 0) ? part[t - 1] : 0;
  for (int j = 0; j < 100; ++j) {
    int dv = deg[base + j];
    offs[base + j] = run;
    norm[base + j] = rsqrtf((float)(dv + 1));
    run += dv;
  }
  if (t == 255) offs[NTOT] = part[255];
}

DI void conv_body(int bx, const float* x1, const float* x2,
                  const float* w3, const float* b3, const float* w5, const float* b5,
                  const float* w7, const float* b7, ushort* c, float* xs /*LDS [16][136]*/) {
  const int t = threadIdx.x;
  const int rowi = t >> 4;
  const int idx = t & 15;
  int r = bx * 16 + rowi;
  int br = r >= NTOT;
  int rr = r - br * NTOT;
  const float* x = br ? x2 : x1;
  int b = rr / 100, node = rr - b * 100;

  float* row = xs + rowi * 136;
  const int w0 = idx * 8;
  float4 v0 = *reinterpret_cast<const float4*>(x + (size_t)rr * WIN + w0);
  float4 v1 = *reinterpret_cast<const float4*>(x + (size_t)rr * WIN + w0 + 4);
  *reinterpret_cast<float4*>(&row[4 + w0]) = v0;
  *reinterpret_cast<float4*>(&row[4 + w0 + 4]) = v1;
  if (idx == 0) { row[0] = 0.f; row[1] = 0.f; row[2] = 0.f; row[3] = 0.f; }
  if (idx == 15) { row[132] = 0.f; row[133] = 0.f; row[134] = 0.f; row[135] = 0.f; }
  __syncthreads();

  float xv[14];
#pragma unroll
  for (int j = 0; j < 14; ++j) xv[j] = row[1 + w0 + j];

  const float* W3 = w3 + node * 6;  const float* B3 = b3 + node * 2;
  const float* W5 = w5 + node * 10; const float* B5 = b5 + node * 2;
  const float* W7 = w7 + node * 14; const float* B7 = b7 + node * 2;
  ushort* out = c + (size_t)br * CB + (size_t)(node * NB + b) * FFK + w0;

#pragma unroll
  for (int ch = 0; ch < 2; ++ch) {
    float k3[3], k5[5], k7[7];
#pragma unroll
    for (int j = 0; j < 3; ++j) k3[j] = W3[ch * 3 + j];
#pragma unroll
    for (int j = 0; j < 5; ++j) k5[j] = W5[ch * 5 + j];
#pragma unroll
    for (int j = 0; j < 7; ++j) k7[j] = W7[ch * 7 + j];
    float bb3 = B3[ch], bb5 = B5[ch], bb7 = B7[ch];
    ushort8v o3, o5, o7;
#pragma unroll
    for (int p = 0; p < 8; ++p) {
      float a3 = bb3, a5 = bb5, a7 = bb7;
#pragma unroll
      for (int j = 0; j < 3; ++j) a3 += k3[j] * xv[p + 2 + j];
#pragma unroll
      for (int j = 0; j < 5; ++j) a5 += k5[j] * xv[p + 1 + j];
#pragma unroll
      for (int j = 0; j < 7; ++j) a7 += k7[j] * xv[p + j];
      o3[p] = f2bf(fmaxf(a3, 0.f));
      o5[p] = f2bf(fmaxf(a5, 0.f));
      o7[p] = f2bf(fmaxf(a7, 0.f));
    }
    *reinterpret_cast<ushort8v*>(out + (0 + ch) * WIN) = o3;
    *reinterpret_cast<ushort8v*>(out + (2 + ch) * WIN) = o5;
    *reinterpret_cast<ushort8v*>(out + (4 + ch) * WIN) = o7;
  }
}

// ---------- BT GEMM body (XOR-swizzled LDS) ----------
template <int MODE>
DI void gemm_body(int bx, int by, const ushort* __restrict__ A, const ushort* __restrict__ A2,
                  const ushort* __restrict__ Bm, ushort* __restrict__ obf,
                  float* __restrict__ of, const float* __restrict__ bias) {
  constexpr int BN = (MODE == 2) ? 64 : 128;
  constexpr int KT = (MODE == 0) ? 12 : (MODE == 1) ? 4 : (MODE == 2) ? 8 : 4;
  constexpr int LDA = (MODE == 0) ? 768 : (MODE == 1) ? 256 : (MODE == 2) ? 256 : 6400;
  constexpr int LDB = (MODE == 0) ? 768 : (MODE == 1) ? 256 : (MODE == 2) ? 512 : 6400;
  constexpr int MF = (MODE == 2) ? 2 : 4;
  constexpr int NF = 4;

  __shared__ ushort As[128 * 64];
  __shared__ ushort Bs[BN * 64];

  const int tid = threadIdx.x, wv = tid >> 6, lane = tid & 63;
  const int j8 = (((lane & 7) ^ (lane >> 3)) - (lane & 7)) * 8;

  int mt = 0, nt = 0, node = 0, kbase = 0, br = 0;
  if constexpr (MODE == 0) {
    int h = bx;
    int s = (h & 7) * 100 + (h >> 3);
    nt = s & 1; int rest = s >> 1;
    mt = rest & 1; int yy = rest >> 1;
    br = yy >= 100; node = yy - br * 100;
  } else if constexpr (MODE == 1) {
    int h = bx;
    int s = (h & 7) * 100 + (h >> 3);
    nt = s & 1; int rest = s >> 1;
    br = rest >= 200; mt = rest - br * 200;
  } else if constexpr (MODE == 2) { mt = bx; node = by; }
  else { mt = bx; kbase = by * 256; }

  const ushort* Ab = nullptr; const ushort* Bb = nullptr;
  if constexpr (MODE == 0) { Ab = A + (size_t)br * CB + (size_t)node * (NB * FFK) + (size_t)mt * 128 * FFK;
                             Bb = Bm + (size_t)node * (GH * FFK) + (size_t)nt * 128 * FFK; }
  else if constexpr (MODE == 1) { Ab = A + (size_t)br * HB + (size_t)mt * 128 * GH;
                                  Bb = Bm + (size_t)nt * 128 * GH; }
  else if constexpr (MODE == 2) { Bb = Bm + (size_t)node * (DH * 512); }
  else { Ab = A + (size_t)mt * 128 * 6400 + kbase; Bb = Bm + kbase; }

  const int wr = (MODE == 2) ? wv : (wv >> 1);
  const int wc = (MODE == 2) ? 0 : (wv & 1);

  f32x4 acc[MF][NF] = {};

  for (int kt = 0; kt < KT; ++kt) {
    const int k0 = kt * 64;
    __syncthreads();
#pragma unroll
    for (int it = 0; it < 4; ++it) {
      int rb = it * 32 + wv * 8;
      int row = rb + (lane >> 3);
      const ushort* gp;
      if constexpr (MODE == 2) {
        int b_ = mt * 128 + row;
        const ushort* src = (k0 < 256) ? A : A2;
        gp = src + (size_t)(b_ * NNODE + node) * GH + (k0 & 255) + (lane & 7) * 8 + j8;
      } else {
        gp = Ab + (size_t)row * LDA + k0 + (lane & 7) * 8 + j8;
      }
      gload16(gp, &As[rb * 64]);
    }
#pragma unroll
    for (int it = 0; it < BN / 32; ++it) {
      int rb = it * 32 + wv * 8;
      int row = rb + (lane >> 3);
      gload16(Bb + (size_t)row * LDB + k0 + (lane & 7) * 8 + j8, &Bs[rb * 64]);
    }
    __syncthreads();
#pragma unroll
    for (int kk = 0; kk < 2; ++kk) {
      const int ch8 = ((kk * 4 + (lane >> 4)) ^ (lane & 7)) * 8;
      bf16x8 af[MF], bfr[NF];
#pragma unroll
      for (int m = 0; m < MF; ++m) {
        int rr = wr * (MF * 16) + m * 16 + (lane & 15);
        af[m] = *reinterpret_cast<const bf16x8*>(&As[rr * 64 + ch8]);
      }
#pragma unroll
      for (int n = 0; n < NF; ++n) {
        int rr = wc * 64 + n * 16 + (lane & 15);
        bfr[n] = *reinterpret_cast<const bf16x8*>(&Bs[rr * 64 + ch8]);
      }
#pragma unroll
      for (int m = 0; m < MF; ++m)
#pragma unroll
        for (int n = 0; n < NF; ++n)
          acc[m][n] = __builtin_amdgcn_mfma_f32_16x16x32_bf16(af[m], bfr[n], acc[m][n], 0, 0, 0);
    }
  }

  const int lrow = (lane >> 4) * 4, lcol = lane & 15;
#pragma unroll
  for (int m = 0; m < MF; ++m) {
#pragma unroll
    for (int n = 0; n < NF; ++n) {
      int cc = wc * 64 + n * 16 + lcol;
#pragma unroll
      for (int rg = 0; rg < 4; ++rg) {
        int rr = wr * (MF * 16) + m * 16 + lrow + rg;
        float val = acc[m][n][rg];
        if constexpr (MODE == 0) {
          int b_ = mt * 128 + rr;
          int col = nt * 128 + cc;
          val = fmaxf(val + bias[node * GH + col], 0.f);
          obf[(size_t)br * HB + (size_t)(b_ * NNODE + node) * GH + col] = f2bf(val);
        } else if constexpr (MODE == 1) {
          int R = mt * 128 + rr;
          int col = nt * 128 + cc;
          obf[(size_t)br * HB + (size_t)R * GH + col] = f2bf(val * bias[br * NTOT + R]);
        } else if constexpr (MODE == 2) {
          int b_ = mt * 128 + rr;
          val = fmaxf(val + bias[node * DH + cc], 0.f);
          obf[(size_t)b_ * (NNODE * DH) + node * DH + cc] = f2bf(val);
        } else {
          int R = mt * 128 + rr;
          if (by == 0) val += bias[cc];
          atomicAdd(&of[R * OUTC + cc], val);
        }
      }
    }
  }
}

// ================= fused launch kernels =================

__global__ __launch_bounds__(256) void fused1_k(
    const float* __restrict__ Wff, const float* __restrict__ Wd,
    const float* __restrict__ Wfc, const float* __restrict__ Wg,
    ushort* __restrict__ Wffb, ushort* __restrict__ Wdb,
    ushort* __restrict__ Wfcb, ushort* __restrict__ Wgb,
    const int* __restrict__ e1d, const int* __restrict__ e2d,
    ushort* __restrict__ rank_local, uint* __restrict__ segcnt,
    const float* __restrict__ x1, const float* __restrict__ x2,
    const float* __restrict__ w3, const float* __restrict__ b3,
    const float* __restrict__ w5, const float* __restrict__ b5,
    const float* __restrict__ w7, const float* __restrict__ b7,
    ushort* __restrict__ c) {
  __shared__ uint smem[NPK];   // 50 KB; conv reuses as float[16][136]
  int bx = blockIdx.x;
  if (bx < 128) histseg_body(bx, e1d, e2d, rank_local, segcnt, smem);
  else if (bx < 3328) conv_body(bx - 128, x1, x2, w3, b3, w5, b5, w7, b7, c, (float*)smem);
  else cvt_body(bx - 3328, Wff, Wd, Wfc, Wg, Wffb, Wdb, Wfcb, Wgb);
}

__global__ __launch_bounds__(256) void segscan_k(const uint* __restrict__ segcnt,
                                                 uint* __restrict__ segbase, int* __restrict__ deg) {
  int set = blockIdx.y;
  int p = blockIdx.x * 256 + threadIdx.x;   // [0, NPK)
  uint lo = 0, hi = 0;
  const uint* sc = segcnt + (size_t)set * NSEG * NPK + p;
  uint* sb = segbase + (size_t)set * NSEG * NPK + p;
  for (int s = 0; s < NSEG; ++s) {
    uint v = sc[(size_t)s * NPK];
    sb[(size_t)s * NPK] = lo | (hi << 16);
    lo += v & 0xffffu; hi += v >> 16;
  }
  reinterpret_cast<int2*>(deg)[set * NPK + p] = make_int2((int)lo, (int)hi);
}

__global__ __launch_bounds__(256) void scan_k(const int* __restrict__ deg,
                                              int* __restrict__ offs, float* __restrict__ nrm) {
  scan_body(blockIdx.x, deg, offs, nrm);
}

__global__ __launch_bounds__(256) void fused3_k(
    const ushort* __restrict__ cbuf, const ushort* __restrict__ Wffb,
    ushort* __restrict__ h, const float* __restrict__ bff,
    const int* __restrict__ e1, const int* __restrict__ e2,
    const int* __restrict__ offs, const ushort* __restrict__ rank_local,
    const uint* __restrict__ segbase, int* __restrict__ csr) {
  if ((int)blockIdx.x < 800)
    gemm_body<0>(blockIdx.x, 0, cbuf, nullptr, Wffb, h, nullptr, bff);
  else
    fill_body(blockIdx.x - 800, e1, e2, offs, rank_local, segbase, csr);
}

template <int MODE>
__global__ __launch_bounds__(256) void gemm_k(const ushort* __restrict__ A, const ushort* __restrict__ A2,
                                              const ushort* __restrict__ Bm, ushort* __restrict__ obf,
                                              float* __restrict__ of, const float* __restrict__ bias) {
  gemm_body<MODE>(blockIdx.x, blockIdx.y, A, A2, Bm, obf, of, bias);
}

// ---------- GCN aggregation, XCD column-sharded, 8-lane group per node ----------
// blockIdx.x = i*8 + c, c = br*4 + slice -> XCD c (per-XCD L2 slice 3.3 MB stays resident).
// 32 groups/block; group g owns node v=i*32+g, accumulates its ~16 edges serially in
// registers (no cross-lane combine), lane covers 8 cols (16 B) of the 64-col slice.
__global__ __launch_bounds__(256) void agg_k(const ushort* __restrict__ xw_, const int* __restrict__ offs_,
                                             const int* __restrict__ csr_, const float* __restrict__ norm_,
                                             const float* __restrict__ bg, ushort* __restrict__ hg_) {
  int bid = blockIdx.x;
  int c = bid & 7;
  int i = bid >> 3;                    // 0..799
  int br = c >> 2, slice = c & 3;
  int g = threadIdx.x >> 3;            // group 0..31 -> node
  int v = i * 32 + g;
  int l8 = threadIdx.x & 7;
  int col = slice * 64 + l8 * 8;       // 8 cols (16 B) per lane

  const ushort* xw = xw_ + (size_t)br * HB;
  const int* offs = offs_ + br * (NTOT + 1);
  const int* csr = csr_ + br * NE;
  const float* norm = norm_ + br * NTOT;
  ushort* hg = hg_ + (size_t)br * HB;
  const uint* base = reinterpret_cast<const uint*>(xw + col);   // row s at base + s*128

  float a[8];
  {   // self loop
    uint4 q = *reinterpret_cast<const uint4*>(base + (size_t)v * (GH / 2));
    a[0] = u2f(q.x << 16); a[1] = u2f(q.x & 0xffff0000u);
    a[2] = u2f(q.y << 16); a[3] = u2f(q.y & 0xffff0000u);
    a[4] = u2f(q.z << 16); a[5] = u2f(q.z & 0xffff0000u);
    a[6] = u2f(q.w << 16); a[7] = u2f(q.w & 0xffff0000u);
  }
  int e0 = offs[v], e1v = offs[v + 1];
  int j = e0;
  for (; j + 1 < e1v; j += 2) {        // 2 gathers in flight per group
    int s0 = csr[j], s1 = csr[j + 1];
    uint4 q0 = *reinterpret_cast<const uint4*>(base + (size_t)s0 * (GH / 2));
    uint4 q1 = *reinterpret_cast<const uint4*>(base + (size_t)s1 * (GH / 2));
    a[0] += u2f(q0.x << 16) + u2f(q1.x << 16);
    a[1] += u2f(q0.x & 0xffff0000u) + u2f(q1.x & 0xffff0000u);
    a[2] += u2f(q0.y << 16) + u2f(q1.y << 16);
    a[3] += u2f(q0.y & 0xffff0000u) + u2f(q1.y & 0xffff0000u);
    a[4] += u2f(q0.z << 16) + u2f(q1.z << 16);
    a[5] += u2f(q0.z & 0xffff0000u) + u2f(q1.z & 0xffff0000u);
    a[6] += u2f(q0.w << 16) + u2f(q1.w << 16);
    a[7] += u2f(q0.w & 0xffff0000u) + u2f(q1.w & 0xffff0000u);
  }
  if (j < e1v) {
    int s0 = csr[j];
    uint4 q0 = *reinterpret_cast<const uint4*>(base + (size_t)s0 * (GH / 2));
    a[0] += u2f(q0.x << 16); a[1] += u2f(q0.x & 0xffff0000u);
    a[2] += u2f(q0.y << 16); a[3] += u2f(q0.y & 0xffff0000u);
    a[4] += u2f(q0.z << 16); a[5] += u2f(q0.z & 0xffff0000u);
    a[6] += u2f(q0.w << 16); a[7] += u2f(q0.w & 0xffff0000u);
  }

  float nv = norm[v];
  float4 bb0 = *reinterpret_cast<const float4*>(bg + col);
  float4 bb1 = *reinterpret_cast<const float4*>(bg + col + 4);
  ushort8v o;
  o[0] = f2bf(fmaxf(nv * a[0] + bb0.x, 0.f));
  o[1] = f2bf(fmaxf(nv * a[1] + bb0.y, 0.f));
  o[2] = f2bf(fmaxf(nv * a[2] + bb0.z, 0.f));
  o[3] = f2bf(fmaxf(nv * a[3] + bb0.w, 0.f));
  o[4] = f2bf(fmaxf(nv * a[4] + bb1.x, 0.f));
  o[5] = f2bf(fmaxf(nv * a[5] + bb1.y, 0.f));
  o[6] = f2bf(fmaxf(nv * a[6] + bb1.z, 0.f));
  o[7] = f2bf(fmaxf(nv * a[7] + bb1.w, 0.f));
  *reinterpret_cast<ushort8v*>(hg + (size_t)v * GH + col) = o;
}

extern "C" void kernel_launch(void* const* d_in, const int* in_sizes, int n_in,
                              void* d_out, int out_size, void* d_ws, size_t ws_size,
                              hipStream_t stream) {
  const float* x1 = (const float*)d_in[0];
  const float* x2 = (const float*)d_in[1];
  const int* e1 = (const int*)d_in[2];
  const int* e2 = (const int*)d_in[3];
  const float* w3 = (const float*)d_in[4];  const float* b3 = (const float*)d_in[5];
  const float* w5 = (const float*)d_in[6];  const float* b5 = (const float*)d_in[7];
  const float* w7 = (const float*)d_in[8];  const float* b7 = (const float*)d_in[9];
  const float* Wff = (const float*)d_in[10]; const float* bff = (const float*)d_in[11];
  const float* Wg = (const float*)d_in[12];  const float* bg = (const float*)d_in[13];
  const float* Wd = (const float*)d_in[14];  const float* bd = (const float*)d_in[15];
  const float* Wfc = (const float*)d_in[16]; const float* bfc = (const float*)d_in[17];
  float* out = (float*)d_out;

  char* ws = (char*)d_ws;
  size_t off = 0;
  auto alloc = [&](size_t bytes) -> char* {
    char* p = ws + off;
    off = (off + bytes + 255) & ~(size_t)255;
    return p;
  };
  ushort* Wffb = (ushort*)alloc(19660800ull * 2);
  ushort* Wdb  = (ushort*)alloc(3276800ull * 2);
  ushort* Wfcb = (ushort*)alloc(819200ull * 2);
  ushort* Wgb  = (ushort*)alloc(65536ull * 2);
  ushort* cbuf = (ushort*)alloc(2 * CB * 2);   // both branches; later aliased as du
  ushort* h    = (ushort*)alloc(2 * HB * 2);   // both branches; later aliased as hg
  ushort* xw   = (ushort*)alloc(2 * HB * 2);   // both branches
  int* deg     = (int*)alloc(2 * NTOT * 4);
  int* offs    = (int*)alloc(2 * (NTOT + 1) * 4);
  ushort* rankl = (ushort*)alloc(2 * NE * 2);
  uint* segcnt  = (uint*)alloc((size_t)2 * NSEG * NPK * 4);
  uint* segbase = (uint*)alloc((size_t)2 * NSEG * NPK * 4);
  int* csr     = (int*)alloc(2 * NE * 4);
  float* nrm   = (float*)alloc(2 * NTOT * 4);
  ushort* du = cbuf;  // alias: cbuf free after FF GEMM

  hipMemsetAsync(out, 0, (size_t)out_size * 4, stream);

  // F1: histseg (LDS histogram, no global atomics) + conv + cvt, all BW-bound
  fused1_k<<<128 + 3200 + CVT_BLKS, 256, 0, stream>>>(
      Wff, Wd, Wfc, Wg, Wffb, Wdb, Wfcb, Wgb,
      e1 + NE, e2 + NE, rankl, segcnt,
      x1, x2, w3, b3, w5, b5, w7, b7, cbuf);
  segscan_k<<<dim3(NPK / 256, 2), 256, 0, stream>>>(segcnt, segbase, deg);
  scan_k<<<2, 256, 0, stream>>>(deg, offs, nrm);
  // F3: FF GEMM || atomic-free CSR fill
  fused3_k<<<4000, 256, 0, stream>>>(cbuf, Wffb, h, bff, e1, e2, offs, rankl, segbase, csr);

  gemm_k<1><<<800, 256, 0, stream>>>(h, nullptr, Wgb, xw, nullptr, nrm);
  // agg: XCD column-sharded, 8-lane group per node; 800 node-groups x 8 combos
  agg_k<<<6400, 256, 0, stream>>>(xw, offs, csr, nrm, bg, h);   // hg overwrites h

  gemm_k<2><<<dim3(2, 100), 256, 0, stream>>>(h, h + HB, Wdb, du, nullptr, bd);
  gemm_k<3><<<dim3(2, 25), 256, 0, stream>>>(du, nullptr, Wfcb, nullptr, out, bfc);
}

// Round 13
// 231.161 us; speedup vs baseline: 1.2220x; 1.0365x over previous
//
#include <hip/hip_runtime.h>

#define DI __device__ __forceinline__

typedef __bf16 bf16_t;
typedef bf16_t bf16x8 __attribute__((ext_vector_type(8)));
typedef float f32x4 __attribute__((ext_vector_type(4)));
typedef ushort ushort8v __attribute__((ext_vector_type(8)));

static constexpr int NNODE = 100, WIN = 128, GH = 256, DH = 64, OUTC = 128, NB = 256;
static constexpr int NTOT = NB * NNODE;   // 25600
static constexpr int NE = 409600;
static constexpr int FFK = 6 * WIN;       // 768
static constexpr size_t CB = (size_t)NNODE * NB * FFK;
static constexpr size_t HB = (size_t)NTOT * GH;
static constexpr int CVT_BLKS = 23264;
static constexpr int NSEG = 64, SEGE = NE / NSEG;      // 64 segs x 6400 edges
static constexpr int NPK = NTOT / 2;                    // 12800 packed counters
static constexpr int NRANGE = 4, RDST = NTOT / NRANGE;  // 4 dst-ranges x 6400 dsts
static constexpr int RPK = RDST / 2;                    // 3200 packed counters per range
static constexpr int HIST_BLKS = 2 * NSEG * NRANGE;     // 512

DI ushort f2bf(float f) {
  union { float f; unsigned u; } v; v.f = f;
  unsigned r = v.u + 0x7fffu + ((v.u >> 16) & 1u);
  return (ushort)(r >> 16);
}
DI float bf2f(ushort s) {
  union { unsigned u; float f; } v; v.u = ((unsigned)s) << 16; return v.f;
}
DI float u2f(uint u) { union { uint u; float f; } v; v.u = u; return v.f; }

DI void gload16(const void* g, void* l) {
  __builtin_amdgcn_global_load_lds((const __attribute__((address_space(1))) void*)g,
                                   (__attribute__((address_space(3))) void*)l, 16, 0, 0);
}

// ================= device bodies =================

DI void cvt_body(int bx, const float* s0, const float* s1, const float* s2, const float* s3,
                 ushort* d0, ushort* d1, ushort* d2, ushort* d3) {
  int j = bx * 256 + threadIdx.x;   // vec4 index
  const float* s; ushort* d;
  if (j < 19660800 / 4) { s = s0; d = d0; }
  else if ((j -= 19660800 / 4) < 3276800 / 4) { s = s1; d = d1; }
  else if ((j -= 3276800 / 4) < 819200 / 4) { s = s2; d = d2; }
  else { j -= 819200 / 4; s = s3; d = d3; }
  float4 v = reinterpret_cast<const float4*>(s)[j];
  ushort4 o;
  o.x = f2bf(v.x); o.y = f2bf(v.y); o.z = f2bf(v.z); o.w = f2bf(v.w);
  reinterpret_cast<ushort4*>(d)[j] = o;
}

// LDS-privatized segmented histogram, dst-range split (4 ranges), 12.8 KB LDS.
// Block (set, seg, range): counts/ranks only dsts in [range*RDST, (range+1)*RDST).
// Each edge is ranked by exactly one block; segcnt global layout is unchanged.
DI void histseg_body(int bx, const int* e1d, const int* e2d,
                     ushort* rank_local, uint* segcnt, uint* cnt /*LDS, RPK*/) {
  int set = bx & 1, seg = (bx >> 1) & (NSEG - 1), range = bx >> 7;
  int tid = threadIdx.x;
  for (int k = tid; k < RPK; k += 256) cnt[k] = 0;
  __syncthreads();
  const int* dstp = (set ? e2d : e1d) + seg * SEGE;
  ushort* rl = rank_local + set * NE + seg * SEGE;
  const int dbase = range * RDST;
#pragma unroll
  for (int k = 0; k < SEGE / 256; ++k) {
    int i = k * 256 + tid;
    uint dl = (uint)(dstp[i] - dbase);
    if (dl < (uint)RDST) {
      uint sh = (dl & 1) * 16;
      uint old = atomicAdd(&cnt[dl >> 1], 1u << sh);
      rl[i] = (ushort)((old >> sh) & 0xffffu);
    }
  }
  __syncthreads();
  uint* sc = segcnt + (size_t)(set * NSEG + seg) * NPK + range * RPK;
  for (int k = tid; k < RPK; k += 256) sc[k] = cnt[k];
}

// atomic-free CSR fill using segment base + local rank
DI void fill_body(int bx, const int* e1, const int* e2, const int* offs,
                  const ushort* rank_local, const uint* segbase, int* csr) {
  int i = bx * 256 + threadIdx.x;          // [0, 2*NE)
  int set = i >= NE;
  int ii = i - set * NE;
  const int* e = set ? e2 : e1;
  int d = e[NE + ii];
  int seg = ii / SEGE;
  uint b32 = segbase[(size_t)(set * NSEG + seg) * NPK + (d >> 1)];
  int base = (b32 >> ((d & 1) * 16)) & 0xffff;
  int pos = offs[set * (NTOT + 1) + d] + base + rank_local[i];
  csr[set * NE + pos] = e[ii];
}

// 256-thread scan over one edge set (100 elems/thread, two-pass)
DI void scan_body(int set, const int* deg_, int* offs_, float* norm_) {
  const int* deg = deg_ + set * NTOT;
  int* offs = offs_ + set * (NTOT + 1);
  float* norm = norm_ + set * NTOT;
  __shared__ int part[256];
  int t = threadIdx.x;
  int base = t * 100;
  int s = 0;
  for (int j = 0; j < 100; ++j) s += deg[base + j];
  part[t] = s;
  __syncthreads();
  for (int d = 1; d < 256; d <<= 1) {
    int vv = (t >= d) ? part[t - d] : 0;
    __syncthreads();
    part[t] += vv;
    __syncthreads();
  }
  int run = (t > 0) ? part[t - 1] : 0;
  for (int j = 0; j < 100; ++j) {
    int dv = deg[base + j];
    offs[base + j] = run;
    norm[base + j] = rsqrtf((float)(dv + 1));
    run += dv;
  }
  if (t == 255) offs[NTOT] = part[255];
}

DI void conv_body(int bx, const float* x1, const float* x2,
                  const float* w3, const float* b3, const float* w5, const float* b5,
                  const float* w7, const float* b7, ushort* c, float* xs /*LDS [16][136]*/) {
  const int t = threadIdx.x;
  const int rowi = t >> 4;
  const int idx = t & 15;
  int r = bx * 16 + rowi;
  int br = r >= NTOT;
  int rr = r - br * NTOT;
  const float* x = br ? x2 : x1;
  int b = rr / 100, node = rr - b * 100;

  float* row = xs + rowi * 136;
  const int w0 = idx * 8;
  float4 v0 = *reinterpret_cast<const float4*>(x + (size_t)rr * WIN + w0);
  float4 v1 = *reinterpret_cast<const float4*>(x + (size_t)rr * WIN + w0 + 4);
  *reinterpret_cast<float4*>(&row[4 + w0]) = v0;
  *reinterpret_cast<float4*>(&row[4 + w0 + 4]) = v1;
  if (idx == 0) { row[0] = 0.f; row[1] = 0.f; row[2] = 0.f; row[3] = 0.f; }
  if (idx == 15) { row[132] = 0.f; row[133] = 0.f; row[134] = 0.f; row[135] = 0.f; }
  __syncthreads();

  float xv[14];
#pragma unroll
  for (int j = 0; j < 14; ++j) xv[j] = row[1 + w0 + j];

  const float* W3 = w3 + node * 6;  const float* B3 = b3 + node * 2;
  const float* W5 = w5 + node * 10; const float* B5 = b5 + node * 2;
  const float* W7 = w7 + node * 14; const float* B7 = b7 + node * 2;
  ushort* out = c + (size_t)br * CB + (size_t)(node * NB + b) * FFK + w0;

#pragma unroll
  for (int ch = 0; ch < 2; ++ch) {
    float k3[3], k5[5], k7[7];
#pragma unroll
    for (int j = 0; j < 3; ++j) k3[j] = W3[ch * 3 + j];
#pragma unroll
    for (int j = 0; j < 5; ++j) k5[j] = W5[ch * 5 + j];
#pragma unroll
    for (int j = 0; j < 7; ++j) k7[j] = W7[ch * 7 + j];
    float bb3 = B3[ch], bb5 = B5[ch], bb7 = B7[ch];
    ushort8v o3, o5, o7;
#pragma unroll
    for (int p = 0; p < 8; ++p) {
      float a3 = bb3, a5 = bb5, a7 = bb7;
#pragma unroll
      for (int j = 0; j < 3; ++j) a3 += k3[j] * xv[p + 2 + j];
#pragma unroll
      for (int j = 0; j < 5; ++j) a5 += k5[j] * xv[p + 1 + j];
#pragma unroll
      for (int j = 0; j < 7; ++j) a7 += k7[j] * xv[p + j];
      o3[p] = f2bf(fmaxf(a3, 0.f));
      o5[p] = f2bf(fmaxf(a5, 0.f));
      o7[p] = f2bf(fmaxf(a7, 0.f));
    }
    *reinterpret_cast<ushort8v*>(out + (0 + ch) * WIN) = o3;
    *reinterpret_cast<ushort8v*>(out + (2 + ch) * WIN) = o5;
    *reinterpret_cast<ushort8v*>(out + (4 + ch) * WIN) = o7;
  }
}

// ---------- BT GEMM body (XOR-swizzled LDS) ----------
template <int MODE>
DI void gemm_body(int bx, int by, const ushort* __restrict__ A, const ushort* __restrict__ A2,
                  const ushort* __restrict__ Bm, ushort* __restrict__ obf,
                  float* __restrict__ of, const float* __restrict__ bias) {
  constexpr int BN = (MODE == 2) ? 64 : 128;
  constexpr int KT = (MODE == 0) ? 12 : (MODE == 1) ? 4 : (MODE == 2) ? 8 : 4;
  constexpr int LDA = (MODE == 0) ? 768 : (MODE == 1) ? 256 : (MODE == 2) ? 256 : 6400;
  constexpr int LDB = (MODE == 0) ? 768 : (MODE == 1) ? 256 : (MODE == 2) ? 512 : 6400;
  constexpr int MF = (MODE == 2) ? 2 : 4;
  constexpr int NF = 4;

  __shared__ ushort As[128 * 64];
  __shared__ ushort Bs[BN * 64];

  const int tid = threadIdx.x, wv = tid >> 6, lane = tid & 63;
  const int j8 = (((lane & 7) ^ (lane >> 3)) - (lane & 7)) * 8;

  int mt = 0, nt = 0, node = 0, kbase = 0, br = 0;
  if constexpr (MODE == 0) {
    int h = bx;
    int s = (h & 7) * 100 + (h >> 3);
    nt = s & 1; int rest = s >> 1;
    mt = rest & 1; int yy = rest >> 1;
    br = yy >= 100; node = yy - br * 100;
  } else if constexpr (MODE == 1) {
    int h = bx;
    int s = (h & 7) * 100 + (h >> 3);
    nt = s & 1; int rest = s >> 1;
    br = rest >= 200; mt = rest - br * 200;
  } else if constexpr (MODE == 2) { mt = bx; node = by; }
  else { mt = bx; kbase = by * 256; }

  const ushort* Ab = nullptr; const ushort* Bb = nullptr;
  if constexpr (MODE == 0) { Ab = A + (size_t)br * CB + (size_t)node * (NB * FFK) + (size_t)mt * 128 * FFK;
                             Bb = Bm + (size_t)node * (GH * FFK) + (size_t)nt * 128 * FFK; }
  else if constexpr (MODE == 1) { Ab = A + (size_t)br * HB + (size_t)mt * 128 * GH;
                                  Bb = Bm + (size_t)nt * 128 * GH; }
  else if constexpr (MODE == 2) { Bb = Bm + (size_t)node * (DH * 512); }
  else { Ab = A + (size_t)mt * 128 * 6400 + kbase; Bb = Bm + kbase; }

  const int wr = (MODE == 2) ? wv : (wv >> 1);
  const int wc = (MODE == 2) ? 0 : (wv & 1);

  f32x4 acc[MF][NF] = {};

  for (int kt = 0; kt < KT; ++kt) {
    const int k0 = kt * 64;
    __syncthreads();
#pragma unroll
    for (int it = 0; it < 4; ++it) {
      int rb = it * 32 + wv * 8;
      int row = rb + (lane >> 3);
      const ushort* gp;
      if constexpr (MODE == 2) {
        int b_ = mt * 128 + row;
        const ushort* src = (k0 < 256) ? A : A2;
        gp = src + (size_t)(b_ * NNODE + node) * GH + (k0 & 255) + (lane & 7) * 8 + j8;
      } else {
        gp = Ab + (size_t)row * LDA + k0 + (lane & 7) * 8 + j8;
      }
      gload16(gp, &As[rb * 64]);
    }
#pragma unroll
    for (int it = 0; it < BN / 32; ++it) {
      int rb = it * 32 + wv * 8;
      int row = rb + (lane >> 3);
      gload16(Bb + (size_t)row * LDB + k0 + (lane & 7) * 8 + j8, &Bs[rb * 64]);
    }
    __syncthreads();
#pragma unroll
    for (int kk = 0; kk < 2; ++kk) {
      const int ch8 = ((kk * 4 + (lane >> 4)) ^ (lane & 7)) * 8;
      bf16x8 af[MF], bfr[NF];
#pragma unroll
      for (int m = 0; m < MF; ++m) {
        int rr = wr * (MF * 16) + m * 16 + (lane & 15);
        af[m] = *reinterpret_cast<const bf16x8*>(&As[rr * 64 + ch8]);
      }
#pragma unroll
      for (int n = 0; n < NF; ++n) {
        int rr = wc * 64 + n * 16 + (lane & 15);
        bfr[n] = *reinterpret_cast<const bf16x8*>(&Bs[rr * 64 + ch8]);
      }
#pragma unroll
      for (int m = 0; m < MF; ++m)
#pragma unroll
        for (int n = 0; n < NF; ++n)
          acc[m][n] = __builtin_amdgcn_mfma_f32_16x16x32_bf16(af[m], bfr[n], acc[m][n], 0, 0, 0);
    }
  }

  const int lrow = (lane >> 4) * 4, lcol = lane & 15;
#pragma unroll
  for (int m = 0; m < MF; ++m) {
#pragma unroll
    for (int n = 0; n < NF; ++n) {
      int cc = wc * 64 + n * 16 + lcol;
#pragma unroll
      for (int rg = 0; rg < 4; ++rg) {
        int rr = wr * (MF * 16) + m * 16 + lrow + rg;
        float val = acc[m][n][rg];
        if constexpr (MODE == 0) {
          int b_ = mt * 128 + rr;
          int col = nt * 128 + cc;
          val = fmaxf(val + bias[node * GH + col], 0.f);
          obf[(size_t)br * HB + (size_t)(b_ * NNODE + node) * GH + col] = f2bf(val);
        } else if constexpr (MODE == 1) {
          int R = mt * 128 + rr;
          int col = nt * 128 + cc;
          obf[(size_t)br * HB + (size_t)R * GH + col] = f2bf(val * bias[br * NTOT + R]);
        } else if constexpr (MODE == 2) {
          int b_ = mt * 128 + rr;
          val = fmaxf(val + bias[node * DH + cc], 0.f);
          obf[(size_t)b_ * (NNODE * DH) + node * DH + cc] = f2bf(val);
        } else {
          int R = mt * 128 + rr;
          if (by == 0) val += bias[cc];
          atomicAdd(&of[R * OUTC + cc], val);
        }
      }
    }
  }
}

// ================= fused launch kernels =================

// F1: [histseg 512][conv 3200][cvt 23264] — LDS 12.8 KB (range-split hist), high occupancy
__global__ __launch_bounds__(256) void fused1_k(
    const float* __restrict__ Wff, const float* __restrict__ Wd,
    const float* __restrict__ Wfc, const float* __restrict__ Wg,
    ushort* __restrict__ Wffb, ushort* __restrict__ Wdb,
    ushort* __restrict__ Wfcb, ushort* __restrict__ Wgb,
    const int* __restrict__ e1d, const int* __restrict__ e2d,
    ushort* __restrict__ rank_local, uint* __restrict__ segcnt,
    const float* __restrict__ x1, const float* __restrict__ x2,
    const float* __restrict__ w3, const float* __restrict__ b3,
    const float* __restrict__ w5, const float* __restrict__ b5,
    const float* __restrict__ w7, const float* __restrict__ b7,
    ushort* __restrict__ c) {
  __shared__ uint smem[RPK];   // 12.8 KB; conv reuses as float[16][136] (8.7 KB)
  int bx = blockIdx.x;
  if (bx < HIST_BLKS) histseg_body(bx, e1d, e2d, rank_local, segcnt, smem);
  else if (bx < HIST_BLKS + 3200) conv_body(bx - HIST_BLKS, x1, x2, w3, b3, w5, b5, w7, b7, c, (float*)smem);
  else cvt_body(bx - HIST_BLKS - 3200, Wff, Wd, Wfc, Wg, Wffb, Wdb, Wfcb, Wgb);
}

__global__ __launch_bounds__(256) void segscan_k(const uint* __restrict__ segcnt,
                                                 uint* __restrict__ segbase, int* __restrict__ deg) {
  int set = blockIdx.y;
  int p = blockIdx.x * 256 + threadIdx.x;   // [0, NPK)
  uint lo = 0, hi = 0;
  const uint* sc = segcnt + (size_t)set * NSEG * NPK + p;
  uint* sb = segbase + (size_t)set * NSEG * NPK + p;
  for (int s = 0; s < NSEG; ++s) {
    uint v = sc[(size_t)s * NPK];
    sb[(size_t)s * NPK] = lo | (hi << 16);
    lo += v & 0xffffu; hi += v >> 16;
  }
  reinterpret_cast<int2*>(deg)[set * NPK + p] = make_int2((int)lo, (int)hi);
}

__global__ __launch_bounds__(256) void scan_k(const int* __restrict__ deg,
                                              int* __restrict__ offs, float* __restrict__ nrm) {
  scan_body(blockIdx.x, deg, offs, nrm);
}

__global__ __launch_bounds__(256) void fused3_k(
    const ushort* __restrict__ cbuf, const ushort* __restrict__ Wffb,
    ushort* __restrict__ h, const float* __restrict__ bff,
    const int* __restrict__ e1, const int* __restrict__ e2,
    const int* __restrict__ offs, const ushort* __restrict__ rank_local,
    const uint* __restrict__ segbase, int* __restrict__ csr) {
  if ((int)blockIdx.x < 800)
    gemm_body<0>(blockIdx.x, 0, cbuf, nullptr, Wffb, h, nullptr, bff);
  else
    fill_body(blockIdx.x - 800, e1, e2, offs, rank_local, segbase, csr);
}

template <int MODE>
__global__ __launch_bounds__(256) void gemm_k(const ushort* __restrict__ A, const ushort* __restrict__ A2,
                                              const ushort* __restrict__ Bm, ushort* __restrict__ obf,
                                              float* __restrict__ of, const float* __restrict__ bias) {
  gemm_body<MODE>(blockIdx.x, blockIdx.y, A, A2, Bm, obf, of, bias);
}

// ---------- GCN aggregation, XCD column-sharded, 8-lane group per node ----------
__global__ __launch_bounds__(256) void agg_k(const ushort* __restrict__ xw_, const int* __restrict__ offs_,
                                             const int* __restrict__ csr_, const float* __restrict__ norm_,
                                             const float* __restrict__ bg, ushort* __restrict__ hg_) {
  int bid = blockIdx.x;
  int c = bid & 7;
  int i = bid >> 3;                    // 0..799
  int br = c >> 2, slice = c & 3;
  int g = threadIdx.x >> 3;            // group 0..31 -> node
  int v = i * 32 + g;
  int l8 = threadIdx.x & 7;
  int col = slice * 64 + l8 * 8;       // 8 cols (16 B) per lane

  const ushort* xw = xw_ + (size_t)br * HB;
  const int* offs = offs_ + br * (NTOT + 1);
  const int* csr = csr_ + br * NE;
  const float* norm = norm_ + br * NTOT;
  ushort* hg = hg_ + (size_t)br * HB;
  const uint* base = reinterpret_cast<const uint*>(xw + col);   // row s at base + s*128

  float a[8];
  {   // self loop
    uint4 q = *reinterpret_cast<const uint4*>(base + (size_t)v * (GH / 2));
    a[0] = u2f(q.x << 16); a[1] = u2f(q.x & 0xffff0000u);
    a[2] = u2f(q.y << 16); a[3] = u2f(q.y & 0xffff0000u);
    a[4] = u2f(q.z << 16); a[5] = u2f(q.z & 0xffff0000u);
    a[6] = u2f(q.w << 16); a[7] = u2f(q.w & 0xffff0000u);
  }
  int e0 = offs[v], e1v = offs[v + 1];
  int j = e0;
  for (; j + 1 < e1v; j += 2) {        // 2 gathers in flight per group
    int s0 = csr[j], s1 = csr[j + 1];
    uint4 q0 = *reinterpret_cast<const uint4*>(base + (size_t)s0 * (GH / 2));
    uint4 q1 = *reinterpret_cast<const uint4*>(base + (size_t)s1 * (GH / 2));
    a[0] += u2f(q0.x << 16) + u2f(q1.x << 16);
    a[1] += u2f(q0.x & 0xffff0000u) + u2f(q1.x & 0xffff0000u);
    a[2] += u2f(q0.y << 16) + u2f(q1.y << 16);
    a[3] += u2f(q0.y & 0xffff0000u) + u2f(q1.y & 0xffff0000u);
    a[4] += u2f(q0.z << 16) + u2f(q1.z << 16);
    a[5] += u2f(q0.z & 0xffff0000u) + u2f(q1.z & 0xffff0000u);
    a[6] += u2f(q0.w << 16) + u2f(q1.w << 16);
    a[7] += u2f(q0.w & 0xffff0000u) + u2f(q1.w & 0xffff0000u);
  }
  if (j < e1v) {
    int s0 = csr[j];
    uint4 q0 = *reinterpret_cast<const uint4*>(base + (size_t)s0 * (GH / 2));
    a[0] += u2f(q0.x << 16); a[1] += u2f(q0.x & 0xffff0000u);
    a[2] += u2f(q0.y << 16); a[3] += u2f(q0.y & 0xffff0000u);
    a[4] += u2f(q0.z << 16); a[5] += u2f(q0.z & 0xffff0000u);
    a[6] += u2f(q0.w << 16); a[7] += u2f(q0.w & 0xffff0000u);
  }

  float nv = norm[v];
  float4 bb0 = *reinterpret_cast<const float4*>(bg + col);
  float4 bb1 = *reinterpret_cast<const float4*>(bg + col + 4);
  ushort8v o;
  o[0] = f2bf(fmaxf(nv * a[0] + bb0.x, 0.f));
  o[1] = f2bf(fmaxf(nv * a[1] + bb0.y, 0.f));
  o[2] = f2bf(fmaxf(nv * a[2] + bb0.z, 0.f));
  o[3] = f2bf(fmaxf(nv * a[3] + bb0.w, 0.f));
  o[4] = f2bf(fmaxf(nv * a[4] + bb1.x, 0.f));
  o[5] = f2bf(fmaxf(nv * a[5] + bb1.y, 0.f));
  o[6] = f2bf(fmaxf(nv * a[6] + bb1.z, 0.f));
  o[7] = f2bf(fmaxf(nv * a[7] + bb1.w, 0.f));
  *reinterpret_cast<ushort8v*>(hg + (size_t)v * GH + col) = o;
}

extern "C" void kernel_launch(void* const* d_in, const int* in_sizes, int n_in,
                              void* d_out, int out_size, void* d_ws, size_t ws_size,
                              hipStream_t stream) {
  const float* x1 = (const float*)d_in[0];
  const float* x2 = (const float*)d_in[1];
  const int* e1 = (const int*)d_in[2];
  const int* e2 = (const int*)d_in[3];
  const float* w3 = (const float*)d_in[4];  const float* b3 = (const float*)d_in[5];
  const float* w5 = (const float*)d_in[6];  const float* b5 = (const float*)d_in[7];
  const float* w7 = (const float*)d_in[8];  const float* b7 = (const float*)d_in[9];
  const float* Wff = (const float*)d_in[10]; const float* bff = (const float*)d_in[11];
  const float* Wg = (const float*)d_in[12];  const float* bg = (const float*)d_in[13];
  const float* Wd = (const float*)d_in[14];  const float* bd = (const float*)d_in[15];
  const float* Wfc = (const float*)d_in[16]; const float* bfc = (const float*)d_in[17];
  float* out = (float*)d_out;

  char* ws = (char*)d_ws;
  size_t off = 0;
  auto alloc = [&](size_t bytes) -> char* {
    char* p = ws + off;
    off = (off + bytes + 255) & ~(size_t)255;
    return p;
  };
  ushort* Wffb = (ushort*)alloc(19660800ull * 2);
  ushort* Wdb  = (ushort*)alloc(3276800ull * 2);
  ushort* Wfcb = (ushort*)alloc(819200ull * 2);
  ushort* Wgb  = (ushort*)alloc(65536ull * 2);
  ushort* cbuf = (ushort*)alloc(2 * CB * 2);   // both branches; later aliased as du
  ushort* h    = (ushort*)alloc(2 * HB * 2);   // both branches; later aliased as hg
  ushort* xw   = (ushort*)alloc(2 * HB * 2);   // both branches
  int* deg     = (int*)alloc(2 * NTOT * 4);
  int* offs    = (int*)alloc(2 * (NTOT + 1) * 4);
  ushort* rankl = (ushort*)alloc(2 * NE * 2);
  uint* segcnt  = (uint*)alloc((size_t)2 * NSEG * NPK * 4);
  uint* segbase = (uint*)alloc((size_t)2 * NSEG * NPK * 4);
  int* csr     = (int*)alloc(2 * NE * 4);
  float* nrm   = (float*)alloc(2 * NTOT * 4);
  ushort* du = cbuf;  // alias: cbuf free after FF GEMM

  hipMemsetAsync(out, 0, (size_t)out_size * 4, stream);

  // F1: range-split histseg + conv + cvt, 12.8 KB LDS, high occupancy
  fused1_k<<<HIST_BLKS + 3200 + CVT_BLKS, 256, 0, stream>>>(
      Wff, Wd, Wfc, Wg, Wffb, Wdb, Wfcb, Wgb,
      e1 + NE, e2 + NE, rankl, segcnt,
      x1, x2, w3, b3, w5, b5, w7, b7, cbuf);
  segscan_k<<<dim3(NPK / 256, 2), 256, 0, stream>>>(segcnt, segbase, deg);
  scan_k<<<2, 256, 0, stream>>>(deg, offs, nrm);
  // F3: FF GEMM || atomic-free CSR fill
  fused3_k<<<4000, 256, 0, stream>>>(cbuf, Wffb, h, bff, e1, e2, offs, rankl, segbase, csr);

  gemm_k<1><<<800, 256, 0, stream>>>(h, nullptr, Wgb, xw, nullptr, nrm);
  // agg: XCD column-sharded, 8-lane group per node; 800 node-groups x 8 combos
  agg_k<<<6400, 256, 0, stream>>>(xw, offs, csr, nrm, bg, h);   // hg overwrites h

  gemm_k<2><<<dim3(2, 100), 256, 0, stream>>>(h, h + HB, Wdb, du, nullptr, bd);
  gemm_k<3><<<dim3(2, 25), 256, 0, stream>>>(du, nullptr, Wfcb, nullptr, out, bfc);
}

// Round 14
// 227.590 us; speedup vs baseline: 1.2412x; 1.0157x over previous
//
#include <hip/hip_runtime.h>

#define DI __device__ __forceinline__

typedef __bf16 bf16_t;
typedef bf16_t bf16x8 __attribute__((ext_vector_type(8)));
typedef float f32x4 __attribute__((ext_vector_type(4)));
typedef ushort ushort8v __attribute__((ext_vector_type(8)));

static constexpr int NNODE = 100, WIN = 128, GH = 256, DH = 64, OUTC = 128, NB = 256;
static constexpr int NTOT = NB * NNODE;   // 25600
static constexpr int NE = 409600;
static constexpr int FFK = 6 * WIN;       // 768
static constexpr size_t CB = (size_t)NNODE * NB * FFK;
static constexpr size_t HB = (size_t)NTOT * GH;
static constexpr int CVT_BLKS = 4064;     // (3276800+819200+65536)/4/256 — Wd, Wfc, Wg only
static constexpr int NSEG = 64, SEGE = NE / NSEG;      // 64 segs x 6400 edges
static constexpr int NPK = NTOT / 2;                    // 12800 packed counters
static constexpr int NRANGE = 4, RDST = NTOT / NRANGE;  // 4 dst-ranges x 6400 dsts
static constexpr int RPK = RDST / 2;                    // 3200 packed counters per range
static constexpr int HIST_BLKS = 2 * NSEG * NRANGE;     // 512

DI ushort f2bf(float f) {
  union { float f; unsigned u; } v; v.f = f;
  unsigned r = v.u + 0x7fffu + ((v.u >> 16) & 1u);
  return (ushort)(r >> 16);
}
DI float bf2f(ushort s) {
  union { unsigned u; float f; } v; v.u = ((unsigned)s) << 16; return v.f;
}
DI float u2f(uint u) { union { uint u; float f; } v; v.u = u; return v.f; }

DI void gload16(const void* g, void* l) {
  __builtin_amdgcn_global_load_lds((const __attribute__((address_space(1))) void*)g,
                                   (__attribute__((address_space(3))) void*)l, 16, 0, 0);
}

// ================= device bodies =================

// cvt: Wd, Wfc, Wg only (Wff converted inside gemm0's B-staging)
DI void cvt_body(int bx, const float* s0, const float* s1, const float* s2,
                 ushort* d0, ushort* d1, ushort* d2) {
  int j = bx * 256 + threadIdx.x;   // vec4 index
  const float* s; ushort* d;
  if (j < 3276800 / 4) { s = s0; d = d0; }
  else if ((j -= 3276800 / 4) < 819200 / 4) { s = s1; d = d1; }
  else { j -= 819200 / 4; s = s2; d = d2; }
  float4 v = reinterpret_cast<const float4*>(s)[j];
  ushort4 o;
  o.x = f2bf(v.x); o.y = f2bf(v.y); o.z = f2bf(v.z); o.w = f2bf(v.w);
  reinterpret_cast<ushort4*>(d)[j] = o;
}

// LDS-privatized segmented histogram, dst-range split (4 ranges), 12.8 KB LDS.
DI void histseg_body(int bx, const int* e1d, const int* e2d,
                     ushort* rank_local, uint* segcnt, uint* cnt /*LDS, RPK*/) {
  int set = bx & 1, seg = (bx >> 1) & (NSEG - 1), range = bx >> 7;
  int tid = threadIdx.x;
  for (int k = tid; k < RPK; k += 256) cnt[k] = 0;
  __syncthreads();
  const int* dstp = (set ? e2d : e1d) + seg * SEGE;
  ushort* rl = rank_local + set * NE + seg * SEGE;
  const int dbase = range * RDST;
#pragma unroll
  for (int k = 0; k < SEGE / 256; ++k) {
    int i = k * 256 + tid;
    uint dl = (uint)(dstp[i] - dbase);
    if (dl < (uint)RDST) {
      uint sh = (dl & 1) * 16;
      uint old = atomicAdd(&cnt[dl >> 1], 1u << sh);
      rl[i] = (ushort)((old >> sh) & 0xffffu);
    }
  }
  __syncthreads();
  uint* sc = segcnt + (size_t)(set * NSEG + seg) * NPK + range * RPK;
  for (int k = tid; k < RPK; k += 256) sc[k] = cnt[k];
}

// atomic-free CSR fill using segment base + local rank
DI void fill_body(int bx, const int* e1, const int* e2, const int* offs,
                  const ushort* rank_local, const uint* segbase, int* csr) {
  int i = bx * 256 + threadIdx.x;          // [0, 2*NE)
  int set = i >= NE;
  int ii = i - set * NE;
  const int* e = set ? e2 : e1;
  int d = e[NE + ii];
  int seg = ii / SEGE;
  uint b32 = segbase[(size_t)(set * NSEG + seg) * NPK + (d >> 1)];
  int base = (b32 >> ((d & 1) * 16)) & 0xffff;
  int pos = offs[set * (NTOT + 1) + d] + base + rank_local[i];
  csr[set * NE + pos] = e[ii];
}

// per-dst running sum over segments (block pb of 50, per set)
DI void segscan_body(int set, int pb, const uint* segcnt, uint* segbase, int* deg) {
  int p = pb * 256 + threadIdx.x;   // [0, NPK)
  uint lo = 0, hi = 0;
  const uint* sc = segcnt + (size_t)set * NSEG * NPK + p;
  uint* sb = segbase + (size_t)set * NSEG * NPK + p;
  for (int s = 0; s < NSEG; ++s) {
    uint v = sc[(size_t)s * NPK];
    sb[(size_t)s * NPK] = lo | (hi << 16);
    lo += v & 0xffffu; hi += v >> 16;
  }
  reinterpret_cast<int2*>(deg)[set * NPK + p] = make_int2((int)lo, (int)hi);
}

// 256-thread scan over one edge set (100 elems/thread, two-pass)
DI void scan_body(int set, const int* deg_, int* offs_, float* norm_) {
  const int* deg = deg_ + set * NTOT;
  int* offs = offs_ + set * (NTOT + 1);
  float* norm = norm_ + set * NTOT;
  __shared__ int part[256];
  int t = threadIdx.x;
  int base = t * 100;
  int s = 0;
  for (int j = 0; j < 100; ++j) s += deg[base + j];
  part[t] = s;
  __syncthreads();
  for (int d = 1; d < 256; d <<= 1) {
    int vv = (t >= d) ? part[t - d] : 0;
    __syncthreads();
    part[t] += vv;
    __syncthreads();
  }
  int run = (t > 0) ? part[t - 1] : 0;
  for (int j = 0; j < 100; ++j) {
    int dv = deg[base + j];
    offs[base + j] = run;
    norm[base + j] = rsqrtf((float)(dv + 1));
    run += dv;
  }
  if (t == 255) offs[NTOT] = part[255];
}

DI void conv_body(int bx, const float* x1, const float* x2,
                  const float* w3, const float* b3, const float* w5, const float* b5,
                  const float* w7, const float* b7, ushort* c, float* xs /*LDS [16][136]*/) {
  const int t = threadIdx.x;
  const int rowi = t >> 4;
  const int idx = t & 15;
  int r = bx * 16 + rowi;
  int br = r >= NTOT;
  int rr = r - br * NTOT;
  const float* x = br ? x2 : x1;
  int b = rr / 100, node = rr - b * 100;

  float* row = xs + rowi * 136;
  const int w0 = idx * 8;
  float4 v0 = *reinterpret_cast<const float4*>(x + (size_t)rr * WIN + w0);
  float4 v1 = *reinterpret_cast<const float4*>(x + (size_t)rr * WIN + w0 + 4);
  *reinterpret_cast<float4*>(&row[4 + w0]) = v0;
  *reinterpret_cast<float4*>(&row[4 + w0 + 4]) = v1;
  if (idx == 0) { row[0] = 0.f; row[1] = 0.f; row[2] = 0.f; row[3] = 0.f; }
  if (idx == 15) { row[132] = 0.f; row[133] = 0.f; row[134] = 0.f; row[135] = 0.f; }
  __syncthreads();

  float xv[14];
#pragma unroll
  for (int j = 0; j < 14; ++j) xv[j] = row[1 + w0 + j];

  const float* W3 = w3 + node * 6;  const float* B3 = b3 + node * 2;
  const float* W5 = w5 + node * 10; const float* B5 = b5 + node * 2;
  const float* W7 = w7 + node * 14; const float* B7 = b7 + node * 2;
  ushort* out = c + (size_t)br * CB + (size_t)(node * NB + b) * FFK + w0;

#pragma unroll
  for (int ch = 0; ch < 2; ++ch) {
    float k3[3], k5[5], k7[7];
#pragma unroll
    for (int j = 0; j < 3; ++j) k3[j] = W3[ch * 3 + j];
#pragma unroll
    for (int j = 0; j < 5; ++j) k5[j] = W5[ch * 5 + j];
#pragma unroll
    for (int j = 0; j < 7; ++j) k7[j] = W7[ch * 7 + j];
    float bb3 = B3[ch], bb5 = B5[ch], bb7 = B7[ch];
    ushort8v o3, o5, o7;
#pragma unroll
    for (int p = 0; p < 8; ++p) {
      float a3 = bb3, a5 = bb5, a7 = bb7;
#pragma unroll
      for (int j = 0; j < 3; ++j) a3 += k3[j] * xv[p + 2 + j];
#pragma unroll
      for (int j = 0; j < 5; ++j) a5 += k5[j] * xv[p + 1 + j];
#pragma unroll
      for (int j = 0; j < 7; ++j) a7 += k7[j] * xv[p + j];
      o3[p] = f2bf(fmaxf(a3, 0.f));
      o5[p] = f2bf(fmaxf(a5, 0.f));
      o7[p] = f2bf(fmaxf(a7, 0.f));
    }
    *reinterpret_cast<ushort8v*>(out + (0 + ch) * WIN) = o3;
    *reinterpret_cast<ushort8v*>(out + (2 + ch) * WIN) = o5;
    *reinterpret_cast<ushort8v*>(out + (4 + ch) * WIN) = o7;
  }
}

// ---------- BT GEMM body (XOR-swizzled LDS) ----------
// MODE 0: B staged from f32 Wff with reg-convert + swizzled ds_write (fused cvt).
template <int MODE>
DI void gemm_body(int bx, int by, const ushort* __restrict__ A, const ushort* __restrict__ A2,
                  const ushort* __restrict__ Bm, const float* __restrict__ Bf32,
                  ushort* __restrict__ obf, float* __restrict__ of, const float* __restrict__ bias) {
  constexpr int BN = (MODE == 2) ? 64 : 128;
  constexpr int KT = (MODE == 0) ? 12 : (MODE == 1) ? 4 : (MODE == 2) ? 8 : 4;
  constexpr int LDA = (MODE == 0) ? 768 : (MODE == 1) ? 256 : (MODE == 2) ? 256 : 6400;
  constexpr int LDB = (MODE == 0) ? 768 : (MODE == 1) ? 256 : (MODE == 2) ? 512 : 6400;
  constexpr int MF = (MODE == 2) ? 2 : 4;
  constexpr int NF = 4;

  __shared__ ushort As[128 * 64];
  __shared__ ushort Bs[BN * 64];

  const int tid = threadIdx.x, wv = tid >> 6, lane = tid & 63;
  const int j8 = (((lane & 7) ^ (lane >> 3)) - (lane & 7)) * 8;

  int mt = 0, nt = 0, node = 0, kbase = 0, br = 0;
  if constexpr (MODE == 0) {
    int h = bx;
    int s = (h & 7) * 100 + (h >> 3);
    nt = s & 1; int rest = s >> 1;
    mt = rest & 1; int yy = rest >> 1;
    br = yy >= 100; node = yy - br * 100;
  } else if constexpr (MODE == 1) {
    int h = bx;
    int s = (h & 7) * 100 + (h >> 3);
    nt = s & 1; int rest = s >> 1;
    br = rest >= 200; mt = rest - br * 200;
  } else if constexpr (MODE == 2) { mt = bx; node = by; }
  else { mt = bx; kbase = by * 256; }

  const ushort* Ab = nullptr; const ushort* Bb = nullptr; const float* Bfp = nullptr;
  if constexpr (MODE == 0) { Ab = A + (size_t)br * CB + (size_t)node * (NB * FFK) + (size_t)mt * 128 * FFK;
                             Bfp = Bf32 + (size_t)node * (GH * FFK) + (size_t)nt * 128 * FFK; }
  else if constexpr (MODE == 1) { Ab = A + (size_t)br * HB + (size_t)mt * 128 * GH;
                                  Bb = Bm + (size_t)nt * 128 * GH; }
  else if constexpr (MODE == 2) { Bb = Bm + (size_t)node * (DH * 512); }
  else { Ab = A + (size_t)mt * 128 * 6400 + kbase; Bb = Bm + kbase; }

  const int wr = (MODE == 2) ? wv : (wv >> 1);
  const int wc = (MODE == 2) ? 0 : (wv & 1);

  f32x4 acc[MF][NF] = {};

  for (int kt = 0; kt < KT; ++kt) {
    const int k0 = kt * 64;
    __syncthreads();
#pragma unroll
    for (int it = 0; it < 4; ++it) {
      int rb = it * 32 + wv * 8;
      int row = rb + (lane >> 3);
      const ushort* gp;
      if constexpr (MODE == 2) {
        int b_ = mt * 128 + row;
        const ushort* src = (k0 < 256) ? A : A2;
        gp = src + (size_t)(b_ * NNODE + node) * GH + (k0 & 255) + (lane & 7) * 8 + j8;
      } else {
        gp = Ab + (size_t)row * LDA + k0 + (lane & 7) * 8 + j8;
      }
      gload16(gp, &As[rb * 64]);
    }
    if constexpr (MODE == 0) {
      // B from f32: reg-convert + swizzled ds_write (source linear; write & read share XOR key)
#pragma unroll
      for (int it = 0; it < 4; ++it) {
        int row = it * 32 + (tid >> 3);
        int cc = tid & 7;
        const float* fp = Bfp + (size_t)row * LDB + k0 + cc * 8;
        float4 v0 = *reinterpret_cast<const float4*>(fp);
        float4 v1 = *reinterpret_cast<const float4*>(fp + 4);
        ushort8v o;
        o[0] = f2bf(v0.x); o[1] = f2bf(v0.y); o[2] = f2bf(v0.z); o[3] = f2bf(v0.w);
        o[4] = f2bf(v1.x); o[5] = f2bf(v1.y); o[6] = f2bf(v1.z); o[7] = f2bf(v1.w);
        *reinterpret_cast<ushort8v*>(&Bs[row * 64 + ((cc ^ (row & 7)) * 8)]) = o;
      }
    } else {
#pragma unroll
      for (int it = 0; it < BN / 32; ++it) {
        int rb = it * 32 + wv * 8;
        int row = rb + (lane >> 3);
        gload16(Bb + (size_t)row * LDB + k0 + (lane & 7) * 8 + j8, &Bs[rb * 64]);
      }
    }
    __syncthreads();
#pragma unroll
    for (int kk = 0; kk < 2; ++kk) {
      const int ch8 = ((kk * 4 + (lane >> 4)) ^ (lane & 7)) * 8;
      bf16x8 af[MF], bfr[NF];
#pragma unroll
      for (int m = 0; m < MF; ++m) {
        int rr = wr * (MF * 16) + m * 16 + (lane & 15);
        af[m] = *reinterpret_cast<const bf16x8*>(&As[rr * 64 + ch8]);
      }
#pragma unroll
      for (int n = 0; n < NF; ++n) {
        int rr = wc * 64 + n * 16 + (lane & 15);
        bfr[n] = *reinterpret_cast<const bf16x8*>(&Bs[rr * 64 + ch8]);
      }
#pragma unroll
      for (int m = 0; m < MF; ++m)
#pragma unroll
        for (int n = 0; n < NF; ++n)
          acc[m][n] = __builtin_amdgcn_mfma_f32_16x16x32_bf16(af[m], bfr[n], acc[m][n], 0, 0, 0);
    }
  }

  const int lrow = (lane >> 4) * 4, lcol = lane & 15;
#pragma unroll
  for (int m = 0; m < MF; ++m) {
#pragma unroll
    for (int n = 0; n < NF; ++n) {
      int cc = wc * 64 + n * 16 + lcol;
#pragma unroll
      for (int rg = 0; rg < 4; ++rg) {
        int rr = wr * (MF * 16) + m * 16 + lrow + rg;
        float val = acc[m][n][rg];
        if constexpr (MODE == 0) {
          int b_ = mt * 128 + rr;
          int col = nt * 128 + cc;
          val = fmaxf(val + bias[node * GH + col], 0.f);
          obf[(size_t)br * HB + (size_t)(b_ * NNODE + node) * GH + col] = f2bf(val);
        } else if constexpr (MODE == 1) {
          int R = mt * 128 + rr;
          int col = nt * 128 + cc;
          obf[(size_t)br * HB + (size_t)R * GH + col] = f2bf(val * bias[br * NTOT + R]);
        } else if constexpr (MODE == 2) {
          int b_ = mt * 128 + rr;
          val = fmaxf(val + bias[node * DH + cc], 0.f);
          obf[(size_t)b_ * (NNODE * DH) + node * DH + cc] = f2bf(val);
        } else {
          int R = mt * 128 + rr;
          if (by == 0) val += bias[cc];
          atomicAdd(&of[R * OUTC + cc], val);
        }
      }
    }
  }
}

// ================= fused launch kernels =================

// F1: [histseg 512][conv 3200][cvt 4064] — LDS 12.8 KB
__global__ __launch_bounds__(256) void fused1_k(
    const float* __restrict__ Wd, const float* __restrict__ Wfc, const float* __restrict__ Wg,
    ushort* __restrict__ Wdb, ushort* __restrict__ Wfcb, ushort* __restrict__ Wgb,
    const int* __restrict__ e1d, const int* __restrict__ e2d,
    ushort* __restrict__ rank_local, uint* __restrict__ segcnt,
    const float* __restrict__ x1, const float* __restrict__ x2,
    const float* __restrict__ w3, const float* __restrict__ b3,
    const float* __restrict__ w5, const float* __restrict__ b5,
    const float* __restrict__ w7, const float* __restrict__ b7,
    ushort* __restrict__ c) {
  __shared__ uint smem[RPK];   // 12.8 KB; conv reuses as float[16][136] (8.7 KB)
  int bx = blockIdx.x;
  if (bx < HIST_BLKS) histseg_body(bx, e1d, e2d, rank_local, segcnt, smem);
  else if (bx < HIST_BLKS + 3200) conv_body(bx - HIST_BLKS, x1, x2, w3, b3, w5, b5, w7, b7, c, (float*)smem);
  else cvt_body(bx - HIST_BLKS - 3200, Wd, Wfc, Wg, Wdb, Wfcb, Wgb);
}

// F3: [gemm0 800 | segscan 100]
__global__ __launch_bounds__(256) void fused3_k(
    const ushort* __restrict__ cbuf, const float* __restrict__ Wff,
    ushort* __restrict__ h, const float* __restrict__ bff,
    const uint* __restrict__ segcnt, uint* __restrict__ segbase, int* __restrict__ deg) {
  if ((int)blockIdx.x < 800)
    gemm_body<0>(blockIdx.x, 0, cbuf, nullptr, nullptr, Wff, h, nullptr, bff);
  else {
    int b = blockIdx.x - 800;
    segscan_body(b / 50, b % 50, segcnt, segbase, deg);
  }
}

__global__ __launch_bounds__(256) void scan_k(const int* __restrict__ deg,
                                              int* __restrict__ offs, float* __restrict__ nrm) {
  scan_body(blockIdx.x, deg, offs, nrm);
}

// F4: [gemm1 800 | fill 3200]
__global__ __launch_bounds__(256) void fused4_k(
    const ushort* __restrict__ h, const ushort* __restrict__ Wgb,
    ushort* __restrict__ xw, const float* __restrict__ nrm,
    const int* __restrict__ e1, const int* __restrict__ e2,
    const int* __restrict__ offs, const ushort* __restrict__ rank_local,
    const uint* __restrict__ segbase, int* __restrict__ csr) {
  if ((int)blockIdx.x < 800)
    gemm_body<1>(blockIdx.x, 0, h, nullptr, Wgb, nullptr, xw, nullptr, nrm);
  else
    fill_body(blockIdx.x - 800, e1, e2, offs, rank_local, segbase, csr);
}

template <int MODE>
__global__ __launch_bounds__(256) void gemm_k(const ushort* __restrict__ A, const ushort* __restrict__ A2,
                                              const ushort* __restrict__ Bm, ushort* __restrict__ obf,
                                              float* __restrict__ of, const float* __restrict__ bias) {
  gemm_body<MODE>(blockIdx.x, blockIdx.y, A, A2, Bm, nullptr, obf, of, bias);
}

// ---------- GCN aggregation, XCD column-sharded, 8-lane group per node ----------
__global__ __launch_bounds__(256) void agg_k(const ushort* __restrict__ xw_, const int* __restrict__ offs_,
                                             const int* __restrict__ csr_, const float* __restrict__ norm_,
                                             const float* __restrict__ bg, ushort* __restrict__ hg_) {
  int bid = blockIdx.x;
  int c = bid & 7;
  int i = bid >> 3;                    // 0..799
  int br = c >> 2, slice = c & 3;
  int g = threadIdx.x >> 3;            // group 0..31 -> node
  int v = i * 32 + g;
  int l8 = threadIdx.x & 7;
  int col = slice * 64 + l8 * 8;       // 8 cols (16 B) per lane

  const ushort* xw = xw_ + (size_t)br * HB;
  const int* offs = offs_ + br * (NTOT + 1);
  const int* csr = csr_ + br * NE;
  const float* norm = norm_ + br * NTOT;
  ushort* hg = hg_ + (size_t)br * HB;
  const uint* base = reinterpret_cast<const uint*>(xw + col);   // row s at base + s*128

  float a[8];
  {   // self loop
    uint4 q = *reinterpret_cast<const uint4*>(base + (size_t)v * (GH / 2));
    a[0] = u2f(q.x << 16); a[1] = u2f(q.x & 0xffff0000u);
    a[2] = u2f(q.y << 16); a[3] = u2f(q.y & 0xffff0000u);
    a[4] = u2f(q.z << 16); a[5] = u2f(q.z & 0xffff0000u);
    a[6] = u2f(q.w << 16); a[7] = u2f(q.w & 0xffff0000u);
  }
  int e0 = offs[v], e1v = offs[v + 1];
  int j = e0;
  for (; j + 1 < e1v; j += 2) {        // 2 gathers in flight per group
    int s0 = csr[j], s1 = csr[j + 1];
    uint4 q0 = *reinterpret_cast<const uint4*>(base + (size_t)s0 * (GH / 2));
    uint4 q1 = *reinterpret_cast<const uint4*>(base + (size_t)s1 * (GH / 2));
    a[0] += u2f(q0.x << 16) + u2f(q1.x << 16);
    a[1] += u2f(q0.x & 0xffff0000u) + u2f(q1.x & 0xffff0000u);
    a[2] += u2f(q0.y << 16) + u2f(q1.y << 16);
    a[3] += u2f(q0.y & 0xffff0000u) + u2f(q1.y & 0xffff0000u);
    a[4] += u2f(q0.z << 16) + u2f(q1.z << 16);
    a[5] += u2f(q0.z & 0xffff0000u) + u2f(q1.z & 0xffff0000u);
    a[6] += u2f(q0.w << 16) + u2f(q1.w << 16);
    a[7] += u2f(q0.w & 0xffff0000u) + u2f(q1.w & 0xffff0000u);
  }
  if (j < e1v) {
    int s0 = csr[j];
    uint4 q0 = *reinterpret_cast<const uint4*>(base + (size_t)s0 * (GH / 2));
    a[0] += u2f(q0.x << 16); a[1] += u2f(q0.x & 0xffff0000u);
    a[2] += u2f(q0.y << 16); a[3] += u2f(q0.y & 0xffff0000u);
    a[4] += u2f(q0.z << 16); a[5] += u2f(q0.z & 0xffff0000u);
    a[6] += u2f(q0.w << 16); a[7] += u2f(q0.w & 0xffff0000u);
  }

  float nv = norm[v];
  float4 bb0 = *reinterpret_cast<const float4*>(bg + col);
  float4 bb1 = *reinterpret_cast<const float4*>(bg + col + 4);
  ushort8v o;
  o[0] = f2bf(fmaxf(nv * a[0] + bb0.x, 0.f));
  o[1] = f2bf(fmaxf(nv * a[1] + bb0.y, 0.f));
  o[2] = f2bf(fmaxf(nv * a[2] + bb0.z, 0.f));
  o[3] = f2bf(fmaxf(nv * a[3] + bb0.w, 0.f));
  o[4] = f2bf(fmaxf(nv * a[4] + bb1.x, 0.f));
  o[5] = f2bf(fmaxf(nv * a[5] + bb1.y, 0.f));
  o[6] = f2bf(fmaxf(nv * a[6] + bb1.z, 0.f));
  o[7] = f2bf(fmaxf(nv * a[7] + bb1.w, 0.f));
  *reinterpret_cast<ushort8v*>(hg + (size_t)v * GH + col) = o;
}

extern "C" void kernel_launch(void* const* d_in, const int* in_sizes, int n_in,
                              void* d_out, int out_size, void* d_ws, size_t ws_size,
                              hipStream_t stream) {
  const float* x1 = (const float*)d_in[0];
  const float* x2 = (const float*)d_in[1];
  const int* e1 = (const int*)d_in[2];
  const int* e2 = (const int*)d_in[3];
  const float* w3 = (const float*)d_in[4];  const float* b3 = (const float*)d_in[5];
  const float* w5 = (const float*)d_in[6];  const float* b5 = (const float*)d_in[7];
  const float* w7 = (const float*)d_in[8];  const float* b7 = (const float*)d_in[9];
  const float* Wff = (const float*)d_in[10]; const float* bff = (const float*)d_in[11];
  const float* Wg = (const float*)d_in[12];  const float* bg = (const float*)d_in[13];
  const float* Wd = (const float*)d_in[14];  const float* bd = (const float*)d_in[15];
  const float* Wfc = (const float*)d_in[16]; const float* bfc = (const float*)d_in[17];
  float* out = (float*)d_out;

  char* ws = (char*)d_ws;
  size_t off = 0;
  auto alloc = [&](size_t bytes) -> char* {
    char* p = ws + off;
    off = (off + bytes + 255) & ~(size_t)255;
    return p;
  };
  ushort* Wdb  = (ushort*)alloc(3276800ull * 2);
  ushort* Wfcb = (ushort*)alloc(819200ull * 2);
  ushort* Wgb  = (ushort*)alloc(65536ull * 2);
  ushort* cbuf = (ushort*)alloc(2 * CB * 2);   // both branches; later aliased as du
  ushort* h    = (ushort*)alloc(2 * HB * 2);   // both branches; later aliased as hg
  ushort* xw   = (ushort*)alloc(2 * HB * 2);   // both branches
  int* deg     = (int*)alloc(2 * NTOT * 4);
  int* offs    = (int*)alloc(2 * (NTOT + 1) * 4);
  ushort* rankl = (ushort*)alloc(2 * NE * 2);
  uint* segcnt  = (uint*)alloc((size_t)2 * NSEG * NPK * 4);
  uint* segbase = (uint*)alloc((size_t)2 * NSEG * NPK * 4);
  int* csr     = (int*)alloc(2 * NE * 4);
  float* nrm   = (float*)alloc(2 * NTOT * 4);
  ushort* du = cbuf;  // alias: cbuf free after FF GEMM

  hipMemsetAsync(out, 0, (size_t)out_size * 4, stream);

  // F1: range-split histseg + conv + cvt(Wd/Wfc/Wg)
  fused1_k<<<HIST_BLKS + 3200 + CVT_BLKS, 256, 0, stream>>>(
      Wd, Wfc, Wg, Wdb, Wfcb, Wgb,
      e1 + NE, e2 + NE, rankl, segcnt,
      x1, x2, w3, b3, w5, b5, w7, b7, cbuf);
  // F3: FF GEMM (B from f32 Wff, fused convert) || segment scan
  fused3_k<<<900, 256, 0, stream>>>(cbuf, Wff, h, bff, segcnt, segbase, deg);
  scan_k<<<2, 256, 0, stream>>>(deg, offs, nrm);
  // F4: GCN linear || atomic-free CSR fill
  fused4_k<<<4000, 256, 0, stream>>>(h, Wgb, xw, nrm, e1, e2, offs, rankl, segbase, csr);

  // agg: XCD column-sharded, 8-lane group per node
  agg_k<<<6400, 256, 0, stream>>>(xw, offs, csr, nrm, bg, h);   // hg overwrites h

  gemm_k<2><<<dim3(2, 100), 256, 0, stream>>>(h, h + HB, Wdb, du, nullptr, bd);
  gemm_k<3><<<dim3(2, 25), 256, 0, stream>>>(du, nullptr, Wfcb, nullptr, out, bfc);
}

// Round 15
// 224.136 us; speedup vs baseline: 1.2603x; 1.0154x over previous
//
#include <hip/hip_runtime.h>

#define DI __device__ __forceinline__

typedef __bf16 bf16_t;
typedef bf16_t bf16x8 __attribute__((ext_vector_type(8)));
typedef float f32x4 __attribute__((ext_vector_type(4)));
typedef ushort ushort8v __attribute__((ext_vector_type(8)));

static constexpr int NNODE = 100, WIN = 128, GH = 256, DH = 64, OUTC = 128, NB = 256;
static constexpr int NTOT = NB * NNODE;   // 25600
static constexpr int NE = 409600;
static constexpr int FFK = 6 * WIN;       // 768
static constexpr size_t CB = (size_t)NNODE * NB * FFK;
static constexpr size_t HB = (size_t)NTOT * GH;
static constexpr int CVT_BLKS = 4064;     // (3276800+819200+65536)/4/256 — Wd, Wfc, Wg only
static constexpr int NSEG = 64, SEGE = NE / NSEG;      // 64 segs x 6400 edges
static constexpr int NPK = NTOT / 2;                    // 12800 packed counters
static constexpr int NRANGE = 4, RDST = NTOT / NRANGE;  // 4 dst-ranges x 6400 dsts
static constexpr int RPK = RDST / 2;                    // 3200 packed counters per range
static constexpr int HIST_BLKS = 2 * NSEG * NRANGE;     // 512

DI ushort f2bf(float f) {
  union { float f; unsigned u; } v; v.f = f;
  unsigned r = v.u + 0x7fffu + ((v.u >> 16) & 1u);
  return (ushort)(r >> 16);
}
DI float bf2f(ushort s) {
  union { unsigned u; float f; } v; v.u = ((unsigned)s) << 16; return v.f;
}
DI float u2f(uint u) { union { uint u; float f; } v; v.u = u; return v.f; }

DI void gload16(const void* g, void* l) {
  __builtin_amdgcn_global_load_lds((const __attribute__((address_space(1))) void*)g,
                                   (__attribute__((address_space(3))) void*)l, 16, 0, 0);
}

// ================= device bodies =================

// cvt: Wd, Wfc, Wg only (Wff converted inside gemm0's B-staging)
DI void cvt_body(int bx, const float* s0, const float* s1, const float* s2,
                 ushort* d0, ushort* d1, ushort* d2) {
  int j = bx * 256 + threadIdx.x;   // vec4 index
  const float* s; ushort* d;
  if (j < 3276800 / 4) { s = s0; d = d0; }
  else if ((j -= 3276800 / 4) < 819200 / 4) { s = s1; d = d1; }
  else { j -= 819200 / 4; s = s2; d = d2; }
  float4 v = reinterpret_cast<const float4*>(s)[j];
  ushort4 o;
  o.x = f2bf(v.x); o.y = f2bf(v.y); o.z = f2bf(v.z); o.w = f2bf(v.w);
  reinterpret_cast<ushort4*>(d)[j] = o;
}

// LDS-privatized segmented histogram, dst-range split (4 ranges), 12.8 KB LDS.
DI void histseg_body(int bx, const int* e1d, const int* e2d,
                     ushort* rank_local, uint* segcnt, uint* cnt /*LDS, RPK*/) {
  int set = bx & 1, seg = (bx >> 1) & (NSEG - 1), range = bx >> 7;
  int tid = threadIdx.x;
  for (int k = tid; k < RPK; k += 256) cnt[k] = 0;
  __syncthreads();
  const int* dstp = (set ? e2d : e1d) + seg * SEGE;
  ushort* rl = rank_local + set * NE + seg * SEGE;
  const int dbase = range * RDST;
#pragma unroll
  for (int k = 0; k < SEGE / 256; ++k) {
    int i = k * 256 + tid;
    uint dl = (uint)(dstp[i] - dbase);
    if (dl < (uint)RDST) {
      uint sh = (dl & 1) * 16;
      uint old = atomicAdd(&cnt[dl >> 1], 1u << sh);
      rl[i] = (ushort)((old >> sh) & 0xffffu);
    }
  }
  __syncthreads();
  uint* sc = segcnt + (size_t)(set * NSEG + seg) * NPK + range * RPK;
  for (int k = tid; k < RPK; k += 256) sc[k] = cnt[k];
}

// atomic-free CSR fill using segment base + local rank
DI void fill_body(int bx, const int* e1, const int* e2, const int* offs,
                  const ushort* rank_local, const uint* segbase, int* csr) {
  int i = bx * 256 + threadIdx.x;          // [0, 2*NE)
  int set = i >= NE;
  int ii = i - set * NE;
  const int* e = set ? e2 : e1;
  int d = e[NE + ii];
  int seg = ii / SEGE;
  uint b32 = segbase[(size_t)(set * NSEG + seg) * NPK + (d >> 1)];
  int base = (b32 >> ((d & 1) * 16)) & 0xffff;
  int pos = offs[set * (NTOT + 1) + d] + base + rank_local[i];
  csr[set * NE + pos] = e[ii];
}

// per-dst running sum over segments (block pb of 50, per set)
DI void segscan_body(int set, int pb, const uint* segcnt, uint* segbase, int* deg) {
  int p = pb * 256 + threadIdx.x;   // [0, NPK)
  uint lo = 0, hi = 0;
  const uint* sc = segcnt + (size_t)set * NSEG * NPK + p;
  uint* sb = segbase + (size_t)set * NSEG * NPK + p;
  for (int s = 0; s < NSEG; ++s) {
    uint v = sc[(size_t)s * NPK];
    sb[(size_t)s * NPK] = lo | (hi << 16);
    lo += v & 0xffffu; hi += v >> 16;
  }
  reinterpret_cast<int2*>(deg)[set * NPK + p] = make_int2((int)lo, (int)hi);
}

// 256-thread scan over one edge set (100 elems/thread, two-pass)
DI void scan_body(int set, const int* deg_, int* offs_, float* norm_) {
  const int* deg = deg_ + set * NTOT;
  int* offs = offs_ + set * (NTOT + 1);
  float* norm = norm_ + set * NTOT;
  __shared__ int part[256];
  int t = threadIdx.x;
  int base = t * 100;
  int s = 0;
  for (int j = 0; j < 100; ++j) s += deg[base + j];
  part[t] = s;
  __syncthreads();
  for (int d = 1; d < 256; d <<= 1) {
    int vv = (t >= d) ? part[t - d] : 0;
    __syncthreads();
    part[t] += vv;
    __syncthreads();
  }
  int run = (t > 0) ? part[t - 1] : 0;
  for (int j = 0; j < 100; ++j) {
    int dv = deg[base + j];
    offs[base + j] = run;
    norm[base + j] = rsqrtf((float)(dv + 1));
    run += dv;
  }
  if (t == 255) offs[NTOT] = part[255];
}

DI void conv_body(int bx, const float* x1, const float* x2,
                  const float* w3, const float* b3, const float* w5, const float* b5,
                  const float* w7, const float* b7, ushort* c, float* xs /*LDS [16][136]*/) {
  const int t = threadIdx.x;
  const int rowi = t >> 4;
  const int idx = t & 15;
  int r = bx * 16 + rowi;
  int br = r >= NTOT;
  int rr = r - br * NTOT;
  const float* x = br ? x2 : x1;
  int b = rr / 100, node = rr - b * 100;

  float* row = xs + rowi * 136;
  const int w0 = idx * 8;
  float4 v0 = *reinterpret_cast<const float4*>(x + (size_t)rr * WIN + w0);
  float4 v1 = *reinterpret_cast<const float4*>(x + (size_t)rr * WIN + w0 + 4);
  *reinterpret_cast<float4*>(&row[4 + w0]) = v0;
  *reinterpret_cast<float4*>(&row[4 + w0 + 4]) = v1;
  if (idx == 0) { row[0] = 0.f; row[1] = 0.f; row[2] = 0.f; row[3] = 0.f; }
  if (idx == 15) { row[132] = 0.f; row[133] = 0.f; row[134] = 0.f; row[135] = 0.f; }
  __syncthreads();

  float xv[14];
#pragma unroll
  for (int j = 0; j < 14; ++j) xv[j] = row[1 + w0 + j];

  const float* W3 = w3 + node * 6;  const float* B3 = b3 + node * 2;
  const float* W5 = w5 + node * 10; const float* B5 = b5 + node * 2;
  const float* W7 = w7 + node * 14; const float* B7 = b7 + node * 2;
  ushort* out = c + (size_t)br * CB + (size_t)(node * NB + b) * FFK + w0;

#pragma unroll
  for (int ch = 0; ch < 2; ++ch) {
    float k3[3], k5[5], k7[7];
#pragma unroll
    for (int j = 0; j < 3; ++j) k3[j] = W3[ch * 3 + j];
#pragma unroll
    for (int j = 0; j < 5; ++j) k5[j] = W5[ch * 5 + j];
#pragma unroll
    for (int j = 0; j < 7; ++j) k7[j] = W7[ch * 7 + j];
    float bb3 = B3[ch], bb5 = B5[ch], bb7 = B7[ch];
    ushort8v o3, o5, o7;
#pragma unroll
    for (int p = 0; p < 8; ++p) {
      float a3 = bb3, a5 = bb5, a7 = bb7;
#pragma unroll
      for (int j = 0; j < 3; ++j) a3 += k3[j] * xv[p + 2 + j];
#pragma unroll
      for (int j = 0; j < 5; ++j) a5 += k5[j] * xv[p + 1 + j];
#pragma unroll
      for (int j = 0; j < 7; ++j) a7 += k7[j] * xv[p + j];
      o3[p] = f2bf(fmaxf(a3, 0.f));
      o5[p] = f2bf(fmaxf(a5, 0.f));
      o7[p] = f2bf(fmaxf(a7, 0.f));
    }
    *reinterpret_cast<ushort8v*>(out + (0 + ch) * WIN) = o3;
    *reinterpret_cast<ushort8v*>(out + (2 + ch) * WIN) = o5;
    *reinterpret_cast<ushort8v*>(out + (4 + ch) * WIN) = o7;
  }
}

// ---------- BT GEMM body (XOR-swizzled LDS) ----------
// MODE 0: BN=64, 1600 blocks; B staged from f32 Wff via T14 prefetch (issue next
//         K-tile's loads after barrier2 so they overlap the MFMA phase).
template <int MODE>
DI void gemm_body(int bx, int by, const ushort* __restrict__ A, const ushort* __restrict__ A2,
                  const ushort* __restrict__ Bm, const float* __restrict__ Bf32,
                  ushort* __restrict__ obf, float* __restrict__ of, const float* __restrict__ bias) {
  constexpr int BN = (MODE == 1 || MODE == 3) ? 128 : 64;
  constexpr int KT = (MODE == 0) ? 12 : (MODE == 1) ? 4 : (MODE == 2) ? 8 : 4;
  constexpr int LDA = (MODE == 0) ? 768 : (MODE == 1) ? 256 : (MODE == 2) ? 256 : 6400;
  constexpr int LDB = (MODE == 0) ? 768 : (MODE == 1) ? 256 : (MODE == 2) ? 512 : 6400;
  constexpr int MF = (MODE == 2) ? 2 : 4;
  constexpr int NF = (MODE == 0) ? 2 : 4;
  constexpr int NTW = (MODE == 0) ? 64 : 128;

  __shared__ ushort As[128 * 64];
  __shared__ ushort Bs[BN * 64];

  const int tid = threadIdx.x, wv = tid >> 6, lane = tid & 63;
  const int j8 = (((lane & 7) ^ (lane >> 3)) - (lane & 7)) * 8;

  int mt = 0, nt = 0, node = 0, kbase = 0, br = 0;
  if constexpr (MODE == 0) {
    int h = bx;                            // 0..1599
    int s = (h & 7) * 200 + (h >> 3);      // bijective (1600 % 8 == 0)
    nt = s & 3; int rest = s >> 2;         // nt: 4 col-tiles of 64
    mt = rest & 1; int yy = rest >> 1;     // 0..199
    br = yy >= 100; node = yy - br * 100;
  } else if constexpr (MODE == 1) {
    int h = bx;
    int s = (h & 7) * 100 + (h >> 3);
    nt = s & 1; int rest = s >> 1;
    br = rest >= 200; mt = rest - br * 200;
  } else if constexpr (MODE == 2) { mt = bx; node = by; }
  else { mt = bx; kbase = by * 256; }

  const ushort* Ab = nullptr; const ushort* Bb = nullptr; const float* Bfp = nullptr;
  if constexpr (MODE == 0) { Ab = A + (size_t)br * CB + (size_t)node * (NB * FFK) + (size_t)mt * 128 * FFK;
                             Bfp = Bf32 + (size_t)node * (GH * FFK) + (size_t)nt * 64 * FFK; }
  else if constexpr (MODE == 1) { Ab = A + (size_t)br * HB + (size_t)mt * 128 * GH;
                                  Bb = Bm + (size_t)nt * 128 * GH; }
  else if constexpr (MODE == 2) { Bb = Bm + (size_t)node * (DH * 512); }
  else { Ab = A + (size_t)mt * 128 * 6400 + kbase; Bb = Bm + kbase; }

  const int wr = (MODE == 2) ? wv : (wv >> 1);
  const int wc = (MODE == 2) ? 0 : (wv & 1);

  f32x4 acc[MF][NF] = {};

  // MODE 0 B-prefetch registers (2 its x 2 float4)
  float4 pb[4];
  const int prow0 = (tid >> 3), pcc = tid & 7;   // staging coords for MODE 0 B
  if constexpr (MODE == 0) {
#pragma unroll
    for (int it = 0; it < 2; ++it) {
      const float* fp = Bfp + (size_t)(it * 32 + prow0) * LDB + 0 + pcc * 8;
      pb[it * 2]     = *reinterpret_cast<const float4*>(fp);
      pb[it * 2 + 1] = *reinterpret_cast<const float4*>(fp + 4);
    }
  }

  for (int kt = 0; kt < KT; ++kt) {
    const int k0 = kt * 64;
    __syncthreads();
#pragma unroll
    for (int it = 0; it < 4; ++it) {
      int rb = it * 32 + wv * 8;
      int row = rb + (lane >> 3);
      const ushort* gp;
      if constexpr (MODE == 2) {
        int b_ = mt * 128 + row;
        const ushort* src = (k0 < 256) ? A : A2;
        gp = src + (size_t)(b_ * NNODE + node) * GH + (k0 & 255) + (lane & 7) * 8 + j8;
      } else {
        gp = Ab + (size_t)row * LDA + k0 + (lane & 7) * 8 + j8;
      }
      gload16(gp, &As[rb * 64]);
    }
    if constexpr (MODE == 0) {
      // consume prefetched B regs: convert + swizzled ds_write
#pragma unroll
      for (int it = 0; it < 2; ++it) {
        int row = it * 32 + prow0;
        float4 v0 = pb[it * 2], v1 = pb[it * 2 + 1];
        ushort8v o;
        o[0] = f2bf(v0.x); o[1] = f2bf(v0.y); o[2] = f2bf(v0.z); o[3] = f2bf(v0.w);
        o[4] = f2bf(v1.x); o[5] = f2bf(v1.y); o[6] = f2bf(v1.z); o[7] = f2bf(v1.w);
        *reinterpret_cast<ushort8v*>(&Bs[row * 64 + ((pcc ^ (row & 7)) * 8)]) = o;
      }
    } else {
#pragma unroll
      for (int it = 0; it < BN / 32; ++it) {
        int rb = it * 32 + wv * 8;
        int row = rb + (lane >> 3);
        gload16(Bb + (size_t)row * LDB + k0 + (lane & 7) * 8 + j8, &Bs[rb * 64]);
      }
    }
    __syncthreads();
    if constexpr (MODE == 0) {
      if (kt + 1 < KT) {   // T14: issue next K-tile's B loads; latency hides under MFMA
        const int kn = (kt + 1) * 64;
#pragma unroll
        for (int it = 0; it < 2; ++it) {
          const float* fp = Bfp + (size_t)(it * 32 + prow0) * LDB + kn + pcc * 8;
          pb[it * 2]     = *reinterpret_cast<const float4*>(fp);
          pb[it * 2 + 1] = *reinterpret_cast<const float4*>(fp + 4);
        }
      }
    }
#pragma unroll
    for (int kk = 0; kk < 2; ++kk) {
      const int ch8 = ((kk * 4 + (lane >> 4)) ^ (lane & 7)) * 8;
      bf16x8 af[MF], bfr[NF];
#pragma unroll
      for (int m = 0; m < MF; ++m) {
        int rr = wr * (MF * 16) + m * 16 + (lane & 15);
        af[m] = *reinterpret_cast<const bf16x8*>(&As[rr * 64 + ch8]);
      }
#pragma unroll
      for (int n = 0; n < NF; ++n) {
        int rr = wc * (NF * 16) + n * 16 + (lane & 15);
        bfr[n] = *reinterpret_cast<const bf16x8*>(&Bs[rr * 64 + ch8]);
      }
#pragma unroll
      for (int m = 0; m < MF; ++m)
#pragma unroll
        for (int n = 0; n < NF; ++n)
          acc[m][n] = __builtin_amdgcn_mfma_f32_16x16x32_bf16(af[m], bfr[n], acc[m][n], 0, 0, 0);
    }
  }

  const int lrow = (lane >> 4) * 4, lcol = lane & 15;
#pragma unroll
  for (int m = 0; m < MF; ++m) {
#pragma unroll
    for (int n = 0; n < NF; ++n) {
      int cc = wc * (NF * 16) + n * 16 + lcol;
#pragma unroll
      for (int rg = 0; rg < 4; ++rg) {
        int rr = wr * (MF * 16) + m * 16 + lrow + rg;
        float val = acc[m][n][rg];
        if constexpr (MODE == 0) {
          int b_ = mt * 128 + rr;
          int col = nt * NTW + cc;
          val = fmaxf(val + bias[node * GH + col], 0.f);
          obf[(size_t)br * HB + (size_t)(b_ * NNODE + node) * GH + col] = f2bf(val);
        } else if constexpr (MODE == 1) {
          int R = mt * 128 + rr;
          int col = nt * 128 + cc;
          obf[(size_t)br * HB + (size_t)R * GH + col] = f2bf(val * bias[br * NTOT + R]);
        } else if constexpr (MODE == 2) {
          int b_ = mt * 128 + rr;
          val = fmaxf(val + bias[node * DH + cc], 0.f);
          obf[(size_t)b_ * (NNODE * DH) + node * DH + cc] = f2bf(val);
        } else {
          int R = mt * 128 + rr;
          if (by == 0) val += bias[cc];
          atomicAdd(&of[R * OUTC + cc], val);
        }
      }
    }
  }
}

// ================= fused launch kernels =================

// F1: [histseg 512][conv 3200][cvt 4064] — LDS 12.8 KB
__global__ __launch_bounds__(256) void fused1_k(
    const float* __restrict__ Wd, const float* __restrict__ Wfc, const float* __restrict__ Wg,
    ushort* __restrict__ Wdb, ushort* __restrict__ Wfcb, ushort* __restrict__ Wgb,
    const int* __restrict__ e1d, const int* __restrict__ e2d,
    ushort* __restrict__ rank_local, uint* __restrict__ segcnt,
    const float* __restrict__ x1, const float* __restrict__ x2,
    const float* __restrict__ w3, const float* __restrict__ b3,
    const float* __restrict__ w5, const float* __restrict__ b5,
    const float* __restrict__ w7, const float* __restrict__ b7,
    ushort* __restrict__ c) {
  __shared__ uint smem[RPK];   // 12.8 KB; conv reuses as float[16][136] (8.7 KB)
  int bx = blockIdx.x;
  if (bx < HIST_BLKS) histseg_body(bx, e1d, e2d, rank_local, segcnt, smem);
  else if (bx < HIST_BLKS + 3200) conv_body(bx - HIST_BLKS, x1, x2, w3, b3, w5, b5, w7, b7, c, (float*)smem);
  else cvt_body(bx - HIST_BLKS - 3200, Wd, Wfc, Wg, Wdb, Wfcb, Wgb);
}

// F3: [gemm0 1600 | segscan 100]
__global__ __launch_bounds__(256) void fused3_k(
    const ushort* __restrict__ cbuf, const float* __restrict__ Wff,
    ushort* __restrict__ h, const float* __restrict__ bff,
    const uint* __restrict__ segcnt, uint* __restrict__ segbase, int* __restrict__ deg) {
  if ((int)blockIdx.x < 1600)
    gemm_body<0>(blockIdx.x, 0, cbuf, nullptr, nullptr, Wff, h, nullptr, bff);
  else {
    int b = blockIdx.x - 1600;
    segscan_body(b / 50, b % 50, segcnt, segbase, deg);
  }
}

__global__ __launch_bounds__(256) void scan_k(const int* __restrict__ deg,
                                              int* __restrict__ offs, float* __restrict__ nrm) {
  scan_body(blockIdx.x, deg, offs, nrm);
}

// F4: [gemm1 800 | fill 3200]
__global__ __launch_bounds__(256) void fused4_k(
    const ushort* __restrict__ h, const ushort* __restrict__ Wgb,
    ushort* __restrict__ xw, const float* __restrict__ nrm,
    const int* __restrict__ e1, const int* __restrict__ e2,
    const int* __restrict__ offs, const ushort* __restrict__ rank_local,
    const uint* __restrict__ segbase, int* __restrict__ csr) {
  if ((int)blockIdx.x < 800)
    gemm_body<1>(blockIdx.x, 0, h, nullptr, Wgb, nullptr, xw, nullptr, nrm);
  else
    fill_body(blockIdx.x - 800, e1, e2, offs, rank_local, segbase, csr);
}

template <int MODE>
__global__ __launch_bounds__(256) void gemm_k(const ushort* __restrict__ A, const ushort* __restrict__ A2,
                                              const ushort* __restrict__ Bm, ushort* __restrict__ obf,
                                              float* __restrict__ of, const float* __restrict__ bias) {
  gemm_body<MODE>(blockIdx.x, blockIdx.y, A, A2, Bm, nullptr, obf, of, bias);
}

// ---------- GCN aggregation, XCD column-sharded, 8-lane group per node ----------
__global__ __launch_bounds__(256) void agg_k(const ushort* __restrict__ xw_, const int* __restrict__ offs_,
                                             const int* __restrict__ csr_, const float* __restrict__ norm_,
                                             const float* __restrict__ bg, ushort* __restrict__ hg_) {
  int bid = blockIdx.x;
  int c = bid & 7;
  int i = bid >> 3;                    // 0..799
  int br = c >> 2, slice = c & 3;
  int g = threadIdx.x >> 3;            // group 0..31 -> node
  int v = i * 32 + g;
  int l8 = threadIdx.x & 7;
  int col = slice * 64 + l8 * 8;       // 8 cols (16 B) per lane

  const ushort* xw = xw_ + (size_t)br * HB;
  const int* offs = offs_ + br * (NTOT + 1);
  const int* csr = csr_ + br * NE;
  const float* norm = norm_ + br * NTOT;
  ushort* hg = hg_ + (size_t)br * HB;
  const uint* base = reinterpret_cast<const uint*>(xw + col);   // row s at base + s*128

  float a[8];
  {   // self loop
    uint4 q = *reinterpret_cast<const uint4*>(base + (size_t)v * (GH / 2));
    a[0] = u2f(q.x << 16); a[1] = u2f(q.x & 0xffff0000u);
    a[2] = u2f(q.y << 16); a[3] = u2f(q.y & 0xffff0000u);
    a[4] = u2f(q.z << 16); a[5] = u2f(q.z & 0xffff0000u);
    a[6] = u2f(q.w << 16); a[7] = u2f(q.w & 0xffff0000u);
  }
  int e0 = offs[v], e1v = offs[v + 1];
  int j = e0;
  for (; j + 1 < e1v; j += 2) {        // 2 gathers in flight per group
    int s0 = csr[j], s1 = csr[j + 1];
    uint4 q0 = *reinterpret_cast<const uint4*>(base + (size_t)s0 * (GH / 2));
    uint4 q1 = *reinterpret_cast<const uint4*>(base + (size_t)s1 * (GH / 2));
    a[0] += u2f(q0.x << 16) + u2f(q1.x << 16);
    a[1] += u2f(q0.x & 0xffff0000u) + u2f(q1.x & 0xffff0000u);
    a[2] += u2f(q0.y << 16) + u2f(q1.y << 16);
    a[3] += u2f(q0.y & 0xffff0000u) + u2f(q1.y & 0xffff0000u);
    a[4] += u2f(q0.z << 16) + u2f(q1.z << 16);
    a[5] += u2f(q0.z & 0xffff0000u) + u2f(q1.z & 0xffff0000u);
    a[6] += u2f(q0.w << 16) + u2f(q1.w << 16);
    a[7] += u2f(q0.w & 0xffff0000u) + u2f(q1.w & 0xffff0000u);
  }
  if (j < e1v) {
    int s0 = csr[j];
    uint4 q0 = *reinterpret_cast<const uint4*>(base + (size_t)s0 * (GH / 2));
    a[0] += u2f(q0.x << 16); a[1] += u2f(q0.x & 0xffff0000u);
    a[2] += u2f(q0.y << 16); a[3] += u2f(q0.y & 0xffff0000u);
    a[4] += u2f(q0.z << 16); a[5] += u2f(q0.z & 0xffff0000u);
    a[6] += u2f(q0.w << 16); a[7] += u2f(q0.w & 0xffff0000u);
  }

  float nv = norm[v];
  float4 bb0 = *reinterpret_cast<const float4*>(bg + col);
  float4 bb1 = *reinterpret_cast<const float4*>(bg + col + 4);
  ushort8v o;
  o[0] = f2bf(fmaxf(nv * a[0] + bb0.x, 0.f));
  o[1] = f2bf(fmaxf(nv * a[1] + bb0.y, 0.f));
  o[2] = f2bf(fmaxf(nv * a[2] + bb0.z, 0.f));
  o[3] = f2bf(fmaxf(nv * a[3] + bb0.w, 0.f));
  o[4] = f2bf(fmaxf(nv * a[4] + bb1.x, 0.f));
  o[5] = f2bf(fmaxf(nv * a[5] + bb1.y, 0.f));
  o[6] = f2bf(fmaxf(nv * a[6] + bb1.z, 0.f));
  o[7] = f2bf(fmaxf(nv * a[7] + bb1.w, 0.f));
  *reinterpret_cast<ushort8v*>(hg + (size_t)v * GH + col) = o;
}

extern "C" void kernel_launch(void* const* d_in, const int* in_sizes, int n_in,
                              void* d_out, int out_size, void* d_ws, size_t ws_size,
                              hipStream_t stream) {
  const float* x1 = (const float*)d_in[0];
  const float* x2 = (const float*)d_in[1];
  const int* e1 = (const int*)d_in[2];
  const int* e2 = (const int*)d_in[3];
  const float* w3 = (const float*)d_in[4];  const float* b3 = (const float*)d_in[5];
  const float* w5 = (const float*)d_in[6];  const float* b5 = (const float*)d_in[7];
  const float* w7 = (const float*)d_in[8];  const float* b7 = (const float*)d_in[9];
  const float* Wff = (const float*)d_in[10]; const float* bff = (const float*)d_in[11];
  const float* Wg = (const float*)d_in[12];  const float* bg = (const float*)d_in[13];
  const float* Wd = (const float*)d_in[14];  const float* bd = (const float*)d_in[15];
  const float* Wfc = (const float*)d_in[16]; const float* bfc = (const float*)d_in[17];
  float* out = (float*)d_out;

  char* ws = (char*)d_ws;
  size_t off = 0;
  auto alloc = [&](size_t bytes) -> char* {
    char* p = ws + off;
    off = (off + bytes + 255) & ~(size_t)255;
    return p;
  };
  ushort* Wdb  = (ushort*)alloc(3276800ull * 2);
  ushort* Wfcb = (ushort*)alloc(819200ull * 2);
  ushort* Wgb  = (ushort*)alloc(65536ull * 2);
  ushort* cbuf = (ushort*)alloc(2 * CB * 2);   // both branches; later aliased as du
  ushort* h    = (ushort*)alloc(2 * HB * 2);   // both branches; later aliased as hg
  ushort* xw   = (ushort*)alloc(2 * HB * 2);   // both branches
  int* deg     = (int*)alloc(2 * NTOT * 4);
  int* offs    = (int*)alloc(2 * (NTOT + 1) * 4);
  ushort* rankl = (ushort*)alloc(2 * NE * 2);
  uint* segcnt  = (uint*)alloc((size_t)2 * NSEG * NPK * 4);
  uint* segbase = (uint*)alloc((size_t)2 * NSEG * NPK * 4);
  int* csr     = (int*)alloc(2 * NE * 4);
  float* nrm   = (float*)alloc(2 * NTOT * 4);
  ushort* du = cbuf;  // alias: cbuf free after FF GEMM

  hipMemsetAsync(out, 0, (size_t)out_size * 4, stream);

  // F1: range-split histseg + conv + cvt(Wd/Wfc/Wg)
  fused1_k<<<HIST_BLKS + 3200 + CVT_BLKS, 256, 0, stream>>>(
      Wd, Wfc, Wg, Wdb, Wfcb, Wgb,
      e1 + NE, e2 + NE, rankl, segcnt,
      x1, x2, w3, b3, w5, b5, w7, b7, cbuf);
  // F3: FF GEMM (BN=64, T14-prefetched f32 B) || segment scan
  fused3_k<<<1700, 256, 0, stream>>>(cbuf, Wff, h, bff, segcnt, segbase, deg);
  scan_k<<<2, 256, 0, stream>>>(deg, offs, nrm);
  // F4: GCN linear || atomic-free CSR fill
  fused4_k<<<4000, 256, 0, stream>>>(h, Wgb, xw, nrm, e1, e2, offs, rankl, segbase, csr);

  // agg: XCD column-sharded, 8-lane group per node
  agg_k<<<6400, 256, 0, stream>>>(xw, offs, csr, nrm, bg, h);   // hg overwrites h

  gemm_k<2><<<dim3(2, 100), 256, 0, stream>>>(h, h + HB, Wdb, du, nullptr, bd);
  gemm_k<3><<<dim3(2, 25), 256, 0, stream>>>(du, nullptr, Wfcb, nullptr, out, bfc);
}